// Round 14
// baseline (1238.278 us; speedup 1.0000x reference)
//
#include <hip/hip_runtime.h>
#include <hip/hip_bf16.h>
#include <math.h>

#define BB 64
#define TT 256
#define NNODE 21
#define HID 128
#define DMODEL 256
#define DINNER 512
#define NSIGNS 2000
#define BTT (BB*TT)   // 16384

typedef unsigned short u16;
typedef unsigned int u32;
typedef __attribute__((ext_vector_type(8))) short short8;
typedef __attribute__((ext_vector_type(4))) float f32x4;

template<int V> struct IC { static constexpr int v = V; };

__device__ __forceinline__ float siluf(float x){ return x/(1.f+expf(-x)); }
__device__ __forceinline__ u16 f2bf(float x){ __hip_bfloat16 h = __float2bfloat16(x); return *(u16*)&h; }
__device__ __forceinline__ u32 pk2bf(float a, float b){
  float2 f2; f2.x = a; f2.y = b;
  __hip_bfloat162 h2 = __float22bfloat162_rn(f2);
  return *(u32*)&h2;
}
__device__ __forceinline__ float bf2f(u16 u){ return __uint_as_float(((u32)u)<<16); }
__device__ __forceinline__ void gload16(const u16* g, u16* l){
  __builtin_amdgcn_global_load_lds((const __attribute__((address_space(1))) void*)g,
                                   (__attribute__((address_space(3))) void*)l, 16, 0, 0);
}

// ---------- tiled weight transpose -> bf16 [N][K] layouts ----------
// block 944: w_sdT[16][128] = folded attention weights (Bp_h · a_h)
__global__ __launch_bounds__(256) void transpose_w_kernel(
    const float* __restrict__ in_proj, const float* __restrict__ out_proj,
    const float* __restrict__ x_proj, const float* __restrict__ w_out,
    const float* __restrict__ pdm_w, const float* __restrict__ w_fuse,
    const float* __restrict__ w_gat, const float* __restrict__ a_src,
    const float* __restrict__ a_dst, u16* __restrict__ dst)
{
  __shared__ short tl[64*66];
  int bx = blockIdx.x, tid = threadIdx.x;
  if (bx == 944) {
    for (int j = tid; j < 2048; j += 256) {
      int c = j >> 7, i = j & 127;
      float v = 0.f;
      if (c < 8) {
        int which = c >> 2, h = c & 3;
        const float* a = (which ? a_dst : a_src) + h*32;
        const float* wg = w_gat + (size_t)h*4096 + i*32;
        #pragma unroll
        for (int o=0;o<32;++o) v += wg[o]*a[o];
      }
      dst[3850240 + j] = f2bf(v);
    }
    return;
  }
  const float* S = nullptr; size_t soff = 0; int lds = 0, Nsrc = 0;
  size_t doff = 0; int ldd = 0, Nout = 0;
  int tn = 0, tk = 0;
  if (bx < 512) {                       // in_projT
    int j = bx >> 5, tt = bx & 31;
    int l = j >> 2, d = j & 1, zh = (j >> 1) & 1;
    tn = tt >> 2; tk = tt & 3;
    S = in_proj; soff = ((size_t)(l*2+d)*256)*1024 + zh*512; lds = 1024; Nsrc = 512;
    doff = (size_t)l*524288 + (size_t)(zh*1024 + d*512)*256; ldd = 256; Nout = 512;
  } else if (bx < 768) {                // out_projT
    int j = (bx-512) >> 5, tt = (bx-512) & 31;
    int l = j >> 1, d = j & 1;
    tn = tt >> 3; tk = tt & 7;
    S = out_proj; soff = (size_t)(l*2+d)*512*256; lds = 256; Nsrc = 256;
    doff = 2097152 + (size_t)l*262144 + d*512; ldd = 1024; Nout = 256;
  } else if (bx < 896) {                // x_projT compact [l][2][64][512]
    int r = bx - 768;
    if (r >= 64) return;
    int j = r >> 3;
    int l = j >> 1, d = j & 1;
    tn = 0; tk = r & 7;
    S = x_proj; soff = (size_t)(l*2+d)*512*48; lds = 48; Nsrc = 48;
    doff = 3145728 + (size_t)l*131072 + (size_t)d*32768; ldd = 512; Nout = 64;
  } else if (bx < 904) {                // w_outT
    int tt = bx-896; tn = tt>>1; tk = tt&1;
    S = w_out; soff = 0; lds = 256; Nsrc = 256;
    doff = 3670016; ldd = 128; Nout = 256;
  } else if (bx < 920) {                // wbigT (pdm_w)
    int j = (bx-904)>>2, tt = (bx-904)&3;
    tn = 0; tk = tt;
    S = pdm_w; soff = (size_t)j*16384; lds = 64; Nsrc = 64;
    doff = 3702784 + (size_t)j*16384; ldd = 256; Nout = 64;
  } else if (bx < 936) {                // w_fuseT
    int tt = bx-920; tn = tt>>2; tk = tt&3;
    S = w_fuse; soff = 0; lds = 256; Nsrc = 256;
    doff = 3768320; ldd = 256; Nout = 256;
  } else {                              // BpT
    int j = (bx-936)>>1, tt = (bx-936)&1;
    tn = 0; tk = tt;
    S = w_gat; soff = (size_t)j*4096; lds = 32; Nsrc = 32;
    doff = 3833856 + (size_t)j*4096; ldd = 128; Nout = 32;
  }
  int n0 = tn*64, k0 = tk*64;
  #pragma unroll
  for (int i=0;i<16;++i){
    int kk = i*4 + (tid>>6), nn = tid&63;
    float v = (n0+nn < Nsrc) ? S[soff + (size_t)(k0+kk)*lds + n0+nn] : 0.f;
    tl[nn*66+kk] = (short)f2bf(v);
  }
  __syncthreads();
  #pragma unroll
  for (int i=0;i<16;++i){
    int nn = i*4 + (tid>>6), kk = tid&63;
    if (n0+nn < Nout) dst[doff + (size_t)(n0+nn)*ldd + k0+kk] = (u16)tl[nn*66+kk];
  }
}

// ---------- AGAN: hm/agg/sd via MFMA (r12 softmax structure) ----------
__global__ __launch_bounds__(256) void agan_kernel(
    const float* __restrict__ x, const float* __restrict__ w_in, const float* __restrict__ b_in,
    const u16* __restrict__ bpt, const u16* __restrict__ wsd,
    u16* __restrict__ fsum_out)
{
  int bt = blockIdx.x;
  int tid = threadIdx.x;
  int lane = tid & 63, wid = tid >> 6;
  int lr = lane & 15, lq = lane >> 4;
  __shared__ float xv[NNODE][4];
  __shared__ __align__(16) short sh0[32*136];
  __shared__ __align__(16) short hmT[128*40];
  __shared__ __align__(16) short alb[4*32*40];
  __shared__ float sd[2][NNODE][4];
  __shared__ float sm[4][NNODE];
  short8 bp[4][2];
  #pragma unroll
  for (int ks=0;ks<4;++ks)
    #pragma unroll
    for (int ct=0;ct<2;++ct)
      bp[ks][ct] = *(const short8*)(bpt + (size_t)(wid*32+ct*16+lr)*128 + ks*32 + lq*8);
  int ii = tid & 127, nn0 = tid >> 7;
  float w0 = w_in[ii], w1 = w_in[128+ii], w2 = w_in[256+ii], bi = b_in[ii];
  if (tid < NNODE*3) xv[tid/3][tid%3] = x[(size_t)bt*63 + tid];
  __syncthreads();
  #pragma unroll
  for (int n = 0; n < 32; n += 2) {
    int nr = n + nn0;
    float v = 0.f;
    if (nr < NNODE)
      v = fmaxf(bi + xv[nr][0]*w0 + xv[nr][1]*w1 + xv[nr][2]*w2, 0.f);
    sh0[nr*136 + ii] = (short)f2bf(v);
  }
  __syncthreads();
  {
    f32x4 g00={},g01={},g10={},g11={},s0v={},s1v={};
    #pragma unroll
    for (int ks=0;ks<4;++ks){
      short8 a0 = *(const short8*)&sh0[(lr   )*136 + ks*32 + lq*8];
      short8 a1 = *(const short8*)&sh0[(16+lr)*136 + ks*32 + lq*8];
      g00 = __builtin_amdgcn_mfma_f32_16x16x32_bf16(a0, bp[ks][0], g00, 0,0,0);
      g01 = __builtin_amdgcn_mfma_f32_16x16x32_bf16(a0, bp[ks][1], g01, 0,0,0);
      g10 = __builtin_amdgcn_mfma_f32_16x16x32_bf16(a1, bp[ks][0], g10, 0,0,0);
      g11 = __builtin_amdgcn_mfma_f32_16x16x32_bf16(a1, bp[ks][1], g11, 0,0,0);
      if (wid == 0) {
        short8 wb = *(const short8*)(wsd + (size_t)lr*128 + ks*32 + lq*8);
        s0v = __builtin_amdgcn_mfma_f32_16x16x32_bf16(a0, wb, s0v, 0,0,0);
        s1v = __builtin_amdgcn_mfma_f32_16x16x32_bf16(a1, wb, s1v, 0,0,0);
      }
    }
    f32x4 gg[2][2] = {{g00,g01},{g10,g11}};
    #pragma unroll
    for (int mt=0;mt<2;++mt)
      #pragma unroll
      for (int ct=0;ct<2;++ct){
        int col = wid*32 + ct*16 + lr;
        int row0 = mt*16 + lq*4;
        u32 wv0 = pk2bf(gg[mt][ct][0], gg[mt][ct][1]);
        u32 wv1 = pk2bf(gg[mt][ct][2], gg[mt][ct][3]);
        *(uint2*)&hmT[col*40 + row0] = make_uint2(wv0,wv1);
      }
    if (wid == 0 && lr < 8) {
      int which = lr >> 2, h = lr & 3;
      #pragma unroll
      for (int r=0;r<4;++r){
        int n0_ = lq*4 + r, n1_ = 16 + lq*4 + r;
        if (n0_ < NNODE) sd[which][n0_][h] = s0v[r];
        if (n1_ < NNODE) sd[which][n1_][h] = s1v[r];
      }
    }
  }
  __syncthreads();
  if (tid < 84) {
    int i = tid >> 2, h = tid & 3;
    float sv = sd[0][i][h], m = -1e30f;
    #pragma unroll
    for (int j=0;j<NNODE;++j){
      float e = sv + sd[1][j][h];
      e = e>=0.f ? e : 0.2f*e;
      m = fmaxf(m,e);
    }
    sm[h][i] = m;
  }
  __syncthreads();
  // exp + rowsum (32-lane shfl reduce; 84*32 is a multiple of 32 so groups complete)
  for (int idx = tid; idx < 84*32; idx += 256) {
    int j = idx & 31, ih = idx >> 5;
    int i = ih >> 2, h = ih & 3;
    float m = sm[h][i];
    float ex = 0.f;
    if (j < NNODE){
      float e = sd[0][i][h] + sd[1][j][h];
      e = e>=0.f ? e : 0.2f*e;
      ex = __expf(e - m);
    }
    alb[(h*32+i)*40 + j] = (short)f2bf(ex);
    float s = ex;
    #pragma unroll
    for (int off=1; off<32; off<<=1) s += __shfl_xor(s, off);
    if (j == 0) sm[h][i] = 1.f/s;
  }
  __syncthreads();
  {
    int h = wid;
    short8 a0 = *(const short8*)&alb[(h*32 + lr     )*40 + lq*8];
    short8 a1 = *(const short8*)&alb[(h*32 + 16 + lr)*40 + lq*8];
    short8 b0 = *(const short8*)&hmT[(h*32 + lr     )*40 + lq*8];
    short8 b1 = *(const short8*)&hmT[(h*32 + 16 + lr)*40 + lq*8];
    f32x4 c00={},c01={},c10={},c11={};
    c00 = __builtin_amdgcn_mfma_f32_16x16x32_bf16(a0,b0,c00,0,0,0);
    c01 = __builtin_amdgcn_mfma_f32_16x16x32_bf16(a0,b1,c01,0,0,0);
    c10 = __builtin_amdgcn_mfma_f32_16x16x32_bf16(a1,b0,c10,0,0,0);
    c11 = __builtin_amdgcn_mfma_f32_16x16x32_bf16(a1,b1,c11,0,0,0);
    f32x4 cc[2][2] = {{c00,c01},{c10,c11}};
    #pragma unroll
    for (int ct=0; ct<2; ++ct){
      int col = h*32 + ct*16 + lr;
      float s = 0.f;
      #pragma unroll
      for (int mt=0; mt<2; ++mt)
        #pragma unroll
        for (int r=0;r<4;++r){
          int n = mt*16 + lq*4 + r;
          if (n < NNODE)
            s += fmaxf(bf2f((u16)sh0[n*136+col]) + cc[mt][ct][r]*sm[h][n], 0.f);
        }
      s += __shfl_xor(s, 16);
      s += __shfl_xor(s, 32);
      if (lq == 0) fsum_out[(size_t)bt*128 + col] = f2bf(s*(1.f/21.f));
    }
  }
}

// ---------- bf16 MFMA GEMM, 128x128 tile, BK=64, XOR-swizzled LDS ----------
template<int ACC, int BIAS, int RELU, int SM>
__global__ __launch_bounds__(256) void gemm_bf16_kernel(
    const u16* __restrict__ A, const u16* __restrict__ BT, const float* __restrict__ bias,
    float* __restrict__ C, u16* __restrict__ C2,
    int M, int N, int K, int lda)
{
  __shared__ __align__(16) short Asl[8192];
  __shared__ __align__(16) short Bsl[8192];
  int tid = threadIdx.x;
  int lane = tid & 63, wid = tid >> 6;
  int wm = wid >> 1, wn = wid & 1;
  int row0 = blockIdx.y*128, col0 = blockIdx.x*128;
  const u16* Ab = A  + (size_t)row0*lda;
  const u16* Bb = BT + (size_t)col0*K;
  f32x4 acc[4][4] = {};
  int lrow = lane & 15, lk = (lane>>4)*8;
  for (int k0 = 0; k0 < K; k0 += 64) {
    #pragma unroll
    for (int is=0; is<4; ++is){
      int li = is*256 + tid;
      int row = li >> 3;
      int c8  = (li & 7) ^ (row & 7);
      gload16(Ab + (size_t)row*lda + k0 + c8*8, (u16*)Asl + ((is<<8)+(wid<<6))*8);
      gload16(Bb + (size_t)row*K   + k0 + c8*8, (u16*)Bsl + ((is<<8)+(wid<<6))*8);
    }
    __syncthreads();
    #pragma unroll
    for (int ksub=0; ksub<2; ++ksub){
      int slot = (ksub*32 + lk) >> 3;
      short8 a[4], b[4];
      #pragma unroll
      for (int i=0;i<4;++i){ int rr=wm*64+i*16+lrow; a[i]=*(const short8*)&Asl[rr*64+((slot^(rr&7))<<3)]; }
      #pragma unroll
      for (int j=0;j<4;++j){ int rr=wn*64+j*16+lrow; b[j]=*(const short8*)&Bsl[rr*64+((slot^(rr&7))<<3)]; }
      #pragma unroll
      for (int i=0;i<4;++i)
        #pragma unroll
        for (int j=0;j<4;++j)
          acc[i][j] = __builtin_amdgcn_mfma_f32_16x16x32_bf16(a[i], b[j], acc[i][j], 0, 0, 0);
    }
    __syncthreads();
  }
  #pragma unroll
  for (int i=0;i<4;++i) {
    int row = row0 + wm*64 + i*16 + (lane>>4)*4;
    #pragma unroll
    for (int j=0;j<4;++j) {
      int col = col0 + wn*64 + j*16 + (lane&15);
      if (col < N) {
        float bv = BIAS ? bias[col] : 0.f;
        #pragma unroll
        for (int r=0;r<4;++r) {
          float v = acc[i][j][r] + bv;
          if (RELU) v = fmaxf(v, 0.f);
          size_t o = (size_t)(row+r)*N + col;
          if (ACC)           C[o] += v;
          else if (SM == 0)  C[o]  = v;
          else               C2[o] = f2bf(v);
        }
      }
    }
  }
}

// ---------- bf16 MFMA GEMM, BM=64 x BN=128, BK=64 (occupancy tile) ----------
template<int ACC, int BIAS, int RELU, int SM, int POOL>
__global__ __launch_bounds__(256) void gemm_bm64_kernel(
    const u16* __restrict__ A, const u16* __restrict__ BT, const float* __restrict__ bias,
    float* __restrict__ C, u16* __restrict__ C2, float* __restrict__ pool,
    int M, int N, int K, int lda)
{
  __shared__ __align__(16) short Asl[4096];    // [64][64]
  __shared__ __align__(16) short Bsl[8192];    // [128][64]
  int tid = threadIdx.x;
  int lane = tid & 63, wid = tid >> 6;
  int wm = wid >> 1, wn = wid & 1;
  int row0 = blockIdx.y*64, col0 = blockIdx.x*128;
  const u16* Ab = A  + (size_t)row0*lda;
  const u16* Bb = BT + (size_t)col0*K;
  f32x4 acc[2][4] = {};
  int lrow = lane & 15, lq = lane >> 4, lk = lq*8;
  for (int k0 = 0; k0 < K; k0 += 64) {
    #pragma unroll
    for (int is=0; is<2; ++is){
      int li = is*256 + tid;
      int row = li >> 3;
      int c8  = (li & 7) ^ (row & 7);
      gload16(Ab + (size_t)row*lda + k0 + c8*8, (u16*)Asl + ((is<<8)+(wid<<6))*8);
    }
    #pragma unroll
    for (int is=0; is<4; ++is){
      int li = is*256 + tid;
      int row = li >> 3;
      int c8  = (li & 7) ^ (row & 7);
      gload16(Bb + (size_t)row*K + k0 + c8*8, (u16*)Bsl + ((is<<8)+(wid<<6))*8);
    }
    __syncthreads();
    #pragma unroll
    for (int ksub=0; ksub<2; ++ksub){
      int slot = (ksub*32 + lk) >> 3;
      short8 a[2], b[4];
      #pragma unroll
      for (int i=0;i<2;++i){ int rr=wm*32+i*16+lrow; a[i]=*(const short8*)&Asl[rr*64+((slot^(rr&7))<<3)]; }
      #pragma unroll
      for (int j=0;j<4;++j){ int rr=wn*64+j*16+lrow; b[j]=*(const short8*)&Bsl[rr*64+((slot^(rr&7))<<3)]; }
      #pragma unroll
      for (int i=0;i<2;++i)
        #pragma unroll
        for (int j=0;j<4;++j)
          acc[i][j] = __builtin_amdgcn_mfma_f32_16x16x32_bf16(a[i], b[j], acc[i][j], 0, 0, 0);
    }
    __syncthreads();
  }
  float colsum[4] = {0.f,0.f,0.f,0.f};
  #pragma unroll
  for (int i=0;i<2;++i) {
    int row = row0 + wm*32 + i*16 + lq*4;
    #pragma unroll
    for (int j=0;j<4;++j) {
      int col = col0 + wn*64 + j*16 + lrow;
      if (col < N) {
        float bv = BIAS ? bias[col] : 0.f;
        #pragma unroll
        for (int r=0;r<4;++r) {
          float v = acc[i][j][r] + bv;
          if (RELU) v = fmaxf(v, 0.f);
          size_t o = (size_t)(row+r)*N + col;
          if (ACC)           C[o] += v;
          else if (SM == 0)  C[o]  = v;
          else               C2[o] = f2bf(v);
          if (POOL) colsum[j] += v;
        }
      }
    }
  }
  if (POOL) {
    float* red = (float*)Asl;
    #pragma unroll
    for (int j=0;j<4;++j) red[tid*4+j] = colsum[j];
    __syncthreads();
    if (tid < 128) {
      int wn_ = tid >> 6, j_ = (tid >> 4) & 3, l15 = tid & 15;
      float s = 0.f;
      #pragma unroll
      for (int wm_=0;wm_<2;++wm_)
        #pragma unroll
        for (int g=0;g<4;++g)
          s += red[(((wm_*2+wn_)*64) + g*16 + l15)*4 + j_];
      pool[(size_t)blockIdx.y*256 + blockIdx.x*128 + tid] = s * (1.f/256.f);
    }
  }
}

// ---------- x_proj GEMM: C[M][128], col-block d = dir; K=512, no padding ----------
__global__ __launch_bounds__(256) void gemm_xproj_kernel(
    const u16* __restrict__ A, const u16* __restrict__ BT, float* __restrict__ C)
{
  __shared__ __align__(16) short Asl[4096];    // [64][64]
  __shared__ __align__(16) short Bsl[4096];    // [64][64]
  int tid = threadIdx.x;
  int lane = tid & 63, wid = tid >> 6;
  int lrow = lane & 15, lq = lane >> 4, lk = lq*8;
  int d = blockIdx.x, row0 = blockIdx.y*64;
  const u16* Ab = A  + (size_t)row0*1024 + d*512;
  const u16* Bb = BT + (size_t)d*32768;
  f32x4 acc[4] = {};
  for (int k0 = 0; k0 < 512; k0 += 64) {
    #pragma unroll
    for (int is=0; is<2; ++is){
      int li = is*256 + tid;
      int row = li >> 3;
      int c8  = (li & 7) ^ (row & 7);
      gload16(Ab + (size_t)row*1024 + k0 + c8*8, (u16*)Asl + ((is<<8)+(wid<<6))*8);
      gload16(Bb + (size_t)row*512  + k0 + c8*8, (u16*)Bsl + ((is<<8)+(wid<<6))*8);
    }
    __syncthreads();
    #pragma unroll
    for (int ksub=0; ksub<2; ++ksub){
      int slot = (ksub*32 + lk) >> 3;
      int arr = wid*16 + lrow;
      short8 av = *(const short8*)&Asl[arr*64 + ((slot^(arr&7))<<3)];
      #pragma unroll
      for (int j=0;j<4;++j){
        int brr = j*16 + lrow;
        short8 bv = *(const short8*)&Bsl[brr*64 + ((slot^(brr&7))<<3)];
        acc[j] = __builtin_amdgcn_mfma_f32_16x16x32_bf16(av, bv, acc[j], 0, 0, 0);
      }
    }
    __syncthreads();
  }
  #pragma unroll
  for (int j=0;j<4;++j){
    int col = d*64 + j*16 + lrow;
    #pragma unroll
    for (int r=0;r<4;++r){
      int row = row0 + wid*16 + lq*4 + r;
      C[(size_t)row*128 + col] = acc[j][r];
    }
  }
}

// ---------- LayerNorm -> bf16 ----------
__global__ __launch_bounds__(256) void ln_kernel(const float* __restrict__ x,
    const float* __restrict__ w, u16* __restrict__ o)
{
  int row = blockIdx.x*4 + (threadIdx.x>>6);
  int lane = threadIdx.x & 63;
  float4 v = *(const float4*)(x + (size_t)row*DMODEL + lane*4);
  float s = v.x+v.y+v.z+v.w;
  #pragma unroll
  for (int off=32;off>=1;off>>=1) s += __shfl_xor(s, off);
  float mu = s * (1.f/256.f);
  float d0=v.x-mu, d1=v.y-mu, d2=v.z-mu, d3=v.w-mu;
  float q = d0*d0+d1*d1+d2*d2+d3*d3;
  #pragma unroll
  for (int off=32;off>=1;off>>=1) q += __shfl_xor(q, off);
  float inv = 1.f/sqrtf(q*(1.f/256.f) + 1e-5f);
  float4 wv = *(const float4*)(w + lane*4);
  uint2 pk; pk.x = pk2bf(d0*inv*wv.x, d1*inv*wv.y); pk.y = pk2bf(d2*inv*wv.z, d3*inv*wv.w);
  *(uint2*)(o + (size_t)row*DMODEL + lane*4) = pk;
}

// ---------- depthwise conv + silu, 8-channel vectorized, both dirs ----------
__global__ __launch_bounds__(256) void conv_kernel(const u16* __restrict__ xz,
    const float* __restrict__ cw, const float* __restrict__ cb,
    u16* __restrict__ ucv)
{
  int idx = blockIdx.x*256 + threadIdx.x;          // BT*128
  int du8 = idx & 127, dir = du8 >> 6, d8 = (du8 & 63) << 3;
  int bt = idx >> 7, t = bt & 255;
  const u16* up = xz + (size_t)(bt - t)*2048 + dir*512 + d8;
  float w[8][4];
  #pragma unroll
  for (int j=0;j<8;++j){
    float4 wv = *(const float4*)(cw + (size_t)dir*2048 + (d8+j)*4);
    w[j][0]=wv.x; w[j][1]=wv.y; w[j][2]=wv.z; w[j][3]=wv.w;
  }
  float s[8];
  float4 cb0 = *(const float4*)(cb + dir*512 + d8);
  float4 cb1 = *(const float4*)(cb + dir*512 + d8 + 4);
  s[0]=cb0.x; s[1]=cb0.y; s[2]=cb0.z; s[3]=cb0.w;
  s[4]=cb1.x; s[5]=cb1.y; s[6]=cb1.z; s[7]=cb1.w;
  if (dir == 0) {
    #pragma unroll
    for (int k=0;k<4;++k){
      int tk = t-3+k;
      if (tk >= 0){
        short8 uv = *(const short8*)(up + (size_t)tk*2048);
        #pragma unroll
        for (int j=0;j<8;++j) s[j] += w[j][k]*bf2f((u16)uv[j]);
      }
    }
  } else {
    #pragma unroll
    for (int kk=0;kk<4;++kk){
      int tk = t+kk;
      if (tk < TT){
        short8 uv = *(const short8*)(up + (size_t)tk*2048);
        #pragma unroll
        for (int j=0;j<8;++j) s[j] += w[j][3-kk]*bf2f((u16)uv[j]);
      }
    }
  }
  short8 o;
  #pragma unroll
  for (int j=0;j<8;++j) o[j] = (short)f2bf(siluf(s[j]));
  *(short8*)(ucv + (size_t)bt*1024 + dir*512 + d8) = o;
}

// ---------- single-pass serial selective scan ----------
// grid (64 b, 4 = d*2 + half), 256 threads; 16-step double-buffered LDS windows
__global__ __launch_bounds__(256) void scan_full_kernel(
    const u16* __restrict__ ucv, const float* __restrict__ xd, const u16* __restrict__ xz,
    const float* __restrict__ dtw, const float* __restrict__ dtb,
    const float* __restrict__ alog, const float* __restrict__ dvec,
    u16* __restrict__ yout)
{
  int b = blockIdx.x, gz = blockIdx.y;
  int d = gz >> 1;
  int tid = threadIdx.x;
  int dd = ((gz & 1) << 8) + tid;
  float wdt[16], Av[16], h[16];
  #pragma unroll
  for (int s=0;s<16;++s){
    wdt[s] = dtw[d*8192 + s*512 + dd];
    Av[s]  = -__expf(alog[d*8192 + dd*16 + s]);
    h[s]   = 0.f;
  }
  float bdt = dtb[d*512 + dd];
  float Dv  = dvec[d*512 + dd];
  bool powok = true;
  #pragma unroll
  for (int s=0;s<16;++s) powok = powok && (fabsf(Av[s] + (float)(s+1)) < 1e-5f*(float)(s+1));
  __shared__ float sxd[2][16][48];
  __shared__ u16 su[2][16][256];
  __shared__ u16 sz[2][16][256];
  const u16* ub = ucv + d*512 + dd;
  const u16* zb = xz + 1024 + d*512 + dd;
  u16* yb = yout + d*512 + dd;
  auto STAGE = [&](int nb, int w){
    #pragma unroll
    for (int q=0;q<16;++q){
      int p = (w<<4)+q, t = d ? 255-p : p;
      size_t row = (size_t)b*TT + t;
      su[nb][q][tid] = ub[row*1024];
      sz[nb][q][tid] = zb[row*2048];
    }
    for (int i = tid; i < 768; i += 256){
      int q = i/48, r = i - q*48;
      int p = (w<<4)+q, t = d ? 255-p : p;
      sxd[nb][q][r] = xd[((size_t)b*TT + t)*128 + d*64 + r];
    }
  };
  STAGE(0, 0);
  int buf = 0;
  for (int w = 0; w < 16; ++w){
    __syncthreads();
    if (w < 15) STAGE(buf^1, w+1);
    auto qloop = [&](auto icpow){
      constexpr int POW = decltype(icpow)::v;
      #pragma unroll 2
      for (int q=0;q<16;++q){
        int p = (w<<4)+q, t = d ? 255-p : p;
        size_t row = (size_t)b*TT + t;
        const float* sr = sxd[buf][q];
        float uc = bf2f(su[buf][q][tid]);
        float zc = bf2f(sz[buf][q][tid]);
        float p0=0.f,p1=0.f,p2=0.f,p3=0.f;
        #pragma unroll
        for (int r=0;r<16;r+=4){
          p0 = fmaf(sr[r+0],wdt[r+0],p0);
          p1 = fmaf(sr[r+1],wdt[r+1],p1);
          p2 = fmaf(sr[r+2],wdt[r+2],p2);
          p3 = fmaf(sr[r+3],wdt[r+3],p3);
        }
        float dtp = bdt + ((p0+p1)+(p2+p3));
        float dt = fmaxf(dtp,0.f) + __logf(1.f + __expf(-fabsf(dtp)));
        float dtu = dt*uc;
        float y0=0.f, y1=0.f;
        if (POW) {
          float rr = __expf(-dt);
          float pw = rr;
          #pragma unroll
          for (int s=0;s<16;++s){
            h[s] = fmaf(pw, h[s], dtu*sr[16+s]);
            y0 = fmaf(h[s], sr[32+s], y0);
            pw *= rr;
          }
        } else {
          #pragma unroll
          for (int s=0;s<16;s+=2){
            float dA0 = __expf(dt*Av[s]);
            float dA1 = __expf(dt*Av[s+1]);
            h[s]   = fmaf(dA0, h[s],   dtu*sr[16+s]);
            h[s+1] = fmaf(dA1, h[s+1], dtu*sr[16+s+1]);
            y0 = fmaf(h[s],sr[32+s],y0); y1 = fmaf(h[s+1],sr[32+s+1],y1);
          }
        }
        float yv = (y0+y1) + uc*Dv;
        float sg = zc / (1.f + __expf(-zc));
        yb[row*2048] = f2bf(yv*sg);
      }
    };
    if (powok) qloop(IC<1>{}); else qloop(IC<0>{});
    buf ^= 1;
  }
}

// ---------- emb: temporal mean + sign GEMV (once per b) ----------
__global__ __launch_bounds__(256) void emb_kernel(const float* __restrict__ xx,
    const float* __restrict__ wsgn, const float* __restrict__ bsgn,
    float* __restrict__ embw, float* __restrict__ out)
{
  int b = blockIdx.x, tid = threadIdx.x;
  __shared__ float mt[256];
  float s0=0.f,s1=0.f,s2=0.f,s3=0.f;
  for (int t=0;t<TT;t+=4){
    s0 += xx[((size_t)b*TT+t  )*DMODEL + tid];
    s1 += xx[((size_t)b*TT+t+1)*DMODEL + tid];
    s2 += xx[((size_t)b*TT+t+2)*DMODEL + tid];
    s3 += xx[((size_t)b*TT+t+3)*DMODEL + tid];
  }
  mt[tid] = (s0+s1+s2+s3)*(1.f/256.f);
  __syncthreads();
  float acc = bsgn[tid];
  for (int i=0;i<DMODEL;++i) acc += mt[i]*wsgn[i*DMODEL + tid];
  embw[b*DMODEL+tid] = acc;
  out[128000 + b*DMODEL + tid] = acc;
}

// ---------- head+sims fused: grid (64, 5); qt<4 sign logits, qt==4 sims ----------
__global__ __launch_bounds__(256) void head_kernel(const float* __restrict__ embw,
    const float* __restrict__ protos, const float* __restrict__ part,
    const float* __restrict__ phs, const float* __restrict__ ploc,
    const float* __restrict__ pmov, const float* __restrict__ pori,
    float* __restrict__ out)
{
  int b = blockIdx.x, qt = blockIdx.y, tid = threadIdx.x;
  __shared__ __align__(16) float e[256];
  __shared__ float red[4];
  if (qt == 4) {
    e[tid] = part[(size_t)(4*b)*256 + tid] + part[(size_t)(4*b+1)*256 + tid]
           + part[(size_t)(4*b+2)*256 + tid] + part[(size_t)(4*b+3)*256 + tid];
    __syncthreads();
    if (tid < 4) {
      float ss = 0.f;
      for (int i=0;i<64;++i){ float q = e[tid*64+i]; ss += q*q; }
      red[tid] = 1.f/(sqrtf(ss)+1e-8f);
    }
    __syncthreads();
    if (tid < 88) {
      int k, pi; const float* P; size_t off; int npk;
      if (tid < 40)      { k=0; pi=tid;    P=phs;  off=144384; npk=40; }
      else if (tid < 60) { k=1; pi=tid-40; P=ploc; off=146944; npk=20; }
      else if (tid < 80) { k=2; pi=tid-60; P=pmov; off=148224; npk=20; }
      else               { k=3; pi=tid-80; P=pori; off=149504; npk=8;  }
      float dot=0.f, ps=0.f;
      for (int i=0;i<64;++i){ float pv = P[pi*64+i]; dot += pv*e[k*64+i]; ps += pv*pv; }
      out[off + (size_t)b*npk + pi] = dot*red[k]/(sqrtf(ps)+1e-8f)*(1.f/0.07f);
    }
    return;
  }
  float acc = embw[b*DMODEL + tid];
  e[tid] = acc;
  __syncthreads();
  float v = acc*acc;
  #pragma unroll
  for (int off=32;off>=1;off>>=1) v += __shfl_xor(v, off);
  if ((tid&63)==0) red[tid>>6] = v;
  __syncthreads();
  float esc = 1.f/(sqrtf(red[0]+red[1]+red[2]+red[3]) + 1e-8f);
  int pend = qt*500 + 500;
  for (int p = qt*500 + tid; p < pend; p += 256) {
    const float* pr = protos + (size_t)p*256;
    float dot=0.f, ps=0.f;
    for (int i=0;i<256;i+=4) {
      float4 pv = *(const float4*)(pr+i);
      float4 ev = *(const float4*)(e+i);
      dot += pv.x*ev.x + pv.y*ev.y + pv.z*ev.z + pv.w*ev.w;
      ps  += pv.x*pv.x + pv.y*pv.y + pv.z*pv.z + pv.w*pv.w;
    }
    out[(size_t)b*NSIGNS + p] = dot*esc/(sqrtf(ps)+1e-8f)*(1.f/0.07f);
  }
}

extern "C" void kernel_launch(void* const* d_in, const int* in_sizes, int n_in,
                              void* d_out, int out_size, void* d_ws, size_t ws_size,
                              hipStream_t stream) {
  const float* x         = (const float*)d_in[0];
  const float* w_in      = (const float*)d_in[1];
  const float* b_in      = (const float*)d_in[2];
  const float* w_gat     = (const float*)d_in[3];
  const float* a_src     = (const float*)d_in[4];
  const float* a_dst     = (const float*)d_in[5];
  const float* w_out     = (const float*)d_in[6];
  const float* b_out     = (const float*)d_in[7];
  const float* pdm_w     = (const float*)d_in[8];
  const float* pdm_b     = (const float*)d_in[9];
  const float* w_fuse    = (const float*)d_in[10];
  const float* b_fuse    = (const float*)d_in[11];
  const float* ln_w      = (const float*)d_in[12];
  const float* in_proj   = (const float*)d_in[13];
  const float* conv_w    = (const float*)d_in[14];
  const float* conv_b    = (const float*)d_in[15];
  const float* x_proj    = (const float*)d_in[16];
  const float* dt_w      = (const float*)d_in[17];
  const float* dt_b      = (const float*)d_in[18];
  const float* A_log     = (const float*)d_in[19];
  const float* Dvec      = (const float*)d_in[20];
  const float* out_proj  = (const float*)d_in[21];
  const float* w_sign    = (const float*)d_in[22];
  const float* b_sign    = (const float*)d_in[23];
  const float* protos    = (const float*)d_in[24];
  const float* phs       = (const float*)d_in[25];
  const float* ploc      = (const float*)d_in[26];
  const float* pmov      = (const float*)d_in[27];
  const float* pori      = (const float*)d_in[28];
  float* out = (float*)d_out;

  // ---- ws layout ----
  float* wsf = (float*)d_ws;
  const size_t f_xx    = 0;                          // 16384*256
  const size_t f_xdbl  = f_xx   + 4194304;           // 16384*128
  const size_t f_part  = f_xdbl + 2097152;           // 256*256
  const size_t f_emb   = f_part + 65536;             // 64*256
  const size_t f_end   = f_emb  + 16384;
  u16* wsu = (u16*)(wsf + f_end);
  const size_t u_xn    = 0;                          // 16384*256
  const size_t u_xz    = u_xn   + 4194304;           // 16384*2048 [u0 u1 z0 z1]; y -> u slots
  const size_t u_ucv   = u_xz   + 33554432;          // 16384*1024
  const size_t u_fsum  = u_ucv  + 16777216;          // 16384*128
  const size_t u_spat  = u_fsum + 2097152;           // 16384*256
  const size_t u_comps = u_spat + 4194304;           // 16384*256
  const size_t u_w     = u_comps+ 4194304;           // weights
  u16* wiT = wsu + u_w;
  u16* woT = wiT + 2097152;
  u16* wxT = woT + 1048576;
  u16* wA  = wxT + 524288;
  u16* wB  = wA  + 32768;
  u16* wF  = wB  + 65536;
  u16* wBp = wF  + 65536;
  u16* wSd = wBp + 16384;              // [16][128] folded sd weights

  transpose_w_kernel<<<945, 256, 0, stream>>>(in_proj, out_proj, x_proj, w_out, pdm_w, w_fuse, w_gat, a_src, a_dst, wsu + u_w);
  agan_kernel<<<BTT, 256, 0, stream>>>(x, w_in, b_in, wBp, wSd, wsu + u_fsum);
  gemm_bm64_kernel<0,1,0,1,0><<<dim3(2,256), 256, 0, stream>>>(wsu+u_fsum, wA, b_out, nullptr, wsu+u_spat, nullptr, BTT, 256, 128, 128);
  gemm_bm64_kernel<0,1,1,1,1><<<dim3(2,256), 256, 0, stream>>>(wsu+u_spat, wB, pdm_b, nullptr, wsu+u_comps, wsf+f_part, BTT, 256, 256, 256);
  gemm_bm64_kernel<0,1,0,0,0><<<dim3(2,256), 256, 0, stream>>>(wsu+u_comps, wF, b_fuse, wsf+f_xx, nullptr, nullptr, BTT, 256, 256, 256);

  for (int l = 0; l < 4; ++l) {
    ln_kernel<<<BTT/4, 256, 0, stream>>>(wsf+f_xx, ln_w + l*DMODEL, wsu+u_xn);
    gemm_bf16_kernel<0,0,0,1><<<dim3(16,128), 256, 0, stream>>>(wsu+u_xn, wiT + (size_t)l*524288,
        nullptr, nullptr, wsu+u_xz, BTT, 2048, 256, 256);
    conv_kernel<<<BTT*128/256, 256, 0, stream>>>(wsu+u_xz, conv_w + (size_t)l*4096,
        conv_b + (size_t)l*1024, wsu+u_ucv);
    gemm_xproj_kernel<<<dim3(2,256), 256, 0, stream>>>(wsu+u_ucv, wxT + (size_t)l*131072, wsf+f_xdbl);
    scan_full_kernel<<<dim3(64,4), 256, 0, stream>>>(wsu+u_ucv, wsf+f_xdbl, wsu+u_xz,
        dt_w + (size_t)l*16384, dt_b + (size_t)l*1024,
        A_log + (size_t)l*16384, Dvec + (size_t)l*1024,
        wsu+u_xz);
    gemm_bm64_kernel<1,0,0,0,0><<<dim3(2,256), 256, 0, stream>>>(wsu+u_xz, woT + (size_t)l*262144,
        nullptr, wsf+f_xx, nullptr, nullptr, BTT, 256, 1024, 2048);
  }

  emb_kernel<<<64, 256, 0, stream>>>(wsf+f_xx, w_sign, b_sign, wsf+f_emb, out);
  head_kernel<<<dim3(64,5), 256, 0, stream>>>(wsf+f_emb, protos, wsf+f_part, phs, ploc, pmov, pori, out);
  (void)in_sizes; (void)n_in; (void)out_size; (void)ws_size;
}

// Round 15
// 1113.222 us; speedup vs baseline: 1.1123x; 1.1123x over previous
//
#include <hip/hip_runtime.h>
#include <hip/hip_bf16.h>
#include <math.h>

#define BB 64
#define TT 256
#define NNODE 21
#define HID 128
#define DMODEL 256
#define DINNER 512
#define NSIGNS 2000
#define BTT (BB*TT)   // 16384

typedef unsigned short u16;
typedef unsigned int u32;
typedef __attribute__((ext_vector_type(8))) short short8;
typedef __attribute__((ext_vector_type(4))) float f32x4;

template<int V> struct IC { static constexpr int v = V; };

__device__ __forceinline__ float siluf(float x){ return x/(1.f+expf(-x)); }
__device__ __forceinline__ u16 f2bf(float x){ __hip_bfloat16 h = __float2bfloat16(x); return *(u16*)&h; }
__device__ __forceinline__ u32 pk2bf(float a, float b){
  float2 f2; f2.x = a; f2.y = b;
  __hip_bfloat162 h2 = __float22bfloat162_rn(f2);
  return *(u32*)&h2;
}
__device__ __forceinline__ float bf2f(u16 u){ return __uint_as_float(((u32)u)<<16); }
__device__ __forceinline__ void gload16(const u16* g, u16* l){
  __builtin_amdgcn_global_load_lds((const __attribute__((address_space(1))) void*)g,
                                   (__attribute__((address_space(3))) void*)l, 16, 0, 0);
}

// ---------- tiled weight transpose -> bf16 [N][K] layouts ----------
// block 944: w_sdT[16][128] = folded attention weights (Bp_h · a_h)
__global__ __launch_bounds__(256) void transpose_w_kernel(
    const float* __restrict__ in_proj, const float* __restrict__ out_proj,
    const float* __restrict__ x_proj, const float* __restrict__ w_out,
    const float* __restrict__ pdm_w, const float* __restrict__ w_fuse,
    const float* __restrict__ w_gat, const float* __restrict__ a_src,
    const float* __restrict__ a_dst, u16* __restrict__ dst)
{
  __shared__ short tl[64*66];
  int bx = blockIdx.x, tid = threadIdx.x;
  if (bx == 944) {
    for (int j = tid; j < 2048; j += 256) {
      int c = j >> 7, i = j & 127;
      float v = 0.f;
      if (c < 8) {
        int which = c >> 2, h = c & 3;
        const float* a = (which ? a_dst : a_src) + h*32;
        const float* wg = w_gat + (size_t)h*4096 + i*32;
        #pragma unroll
        for (int o=0;o<32;++o) v += wg[o]*a[o];
      }
      dst[3850240 + j] = f2bf(v);
    }
    return;
  }
  const float* S = nullptr; size_t soff = 0; int lds = 0, Nsrc = 0;
  size_t doff = 0; int ldd = 0, Nout = 0;
  int tn = 0, tk = 0;
  if (bx < 512) {                       // in_projT
    int j = bx >> 5, tt = bx & 31;
    int l = j >> 2, d = j & 1, zh = (j >> 1) & 1;
    tn = tt >> 2; tk = tt & 3;
    S = in_proj; soff = ((size_t)(l*2+d)*256)*1024 + zh*512; lds = 1024; Nsrc = 512;
    doff = (size_t)l*524288 + (size_t)(zh*1024 + d*512)*256; ldd = 256; Nout = 512;
  } else if (bx < 768) {                // out_projT
    int j = (bx-512) >> 5, tt = (bx-512) & 31;
    int l = j >> 1, d = j & 1;
    tn = tt >> 3; tk = tt & 7;
    S = out_proj; soff = (size_t)(l*2+d)*512*256; lds = 256; Nsrc = 256;
    doff = 2097152 + (size_t)l*262144 + d*512; ldd = 1024; Nout = 256;
  } else if (bx < 896) {                // x_projT compact [l][2][64][512]
    int r = bx - 768;
    if (r >= 64) return;
    int j = r >> 3;
    int l = j >> 1, d = j & 1;
    tn = 0; tk = r & 7;
    S = x_proj; soff = (size_t)(l*2+d)*512*48; lds = 48; Nsrc = 48;
    doff = 3145728 + (size_t)l*131072 + (size_t)d*32768; ldd = 512; Nout = 64;
  } else if (bx < 904) {                // w_outT
    int tt = bx-896; tn = tt>>1; tk = tt&1;
    S = w_out; soff = 0; lds = 256; Nsrc = 256;
    doff = 3670016; ldd = 128; Nout = 256;
  } else if (bx < 920) {                // wbigT (pdm_w)
    int j = (bx-904)>>2, tt = (bx-904)&3;
    tn = 0; tk = tt;
    S = pdm_w; soff = (size_t)j*16384; lds = 64; Nsrc = 64;
    doff = 3702784 + (size_t)j*16384; ldd = 256; Nout = 64;
  } else if (bx < 936) {                // w_fuseT
    int tt = bx-920; tn = tt>>2; tk = tt&3;
    S = w_fuse; soff = 0; lds = 256; Nsrc = 256;
    doff = 3768320; ldd = 256; Nout = 256;
  } else {                              // BpT
    int j = (bx-936)>>1, tt = (bx-936)&1;
    tn = 0; tk = tt;
    S = w_gat; soff = (size_t)j*4096; lds = 32; Nsrc = 32;
    doff = 3833856 + (size_t)j*4096; ldd = 128; Nout = 32;
  }
  int n0 = tn*64, k0 = tk*64;
  #pragma unroll
  for (int i=0;i<16;++i){
    int kk = i*4 + (tid>>6), nn = tid&63;
    float v = (n0+nn < Nsrc) ? S[soff + (size_t)(k0+kk)*lds + n0+nn] : 0.f;
    tl[nn*66+kk] = (short)f2bf(v);
  }
  __syncthreads();
  #pragma unroll
  for (int i=0;i<16;++i){
    int nn = i*4 + (tid>>6), kk = tid&63;
    if (n0+nn < Nout) dst[doff + (size_t)(n0+nn)*ldd + k0+kk] = (u16)tl[nn*66+kk];
  }
}

// ---------- AGAN: hm/agg/sd via MFMA (r12 softmax structure) ----------
__global__ __launch_bounds__(256) void agan_kernel(
    const float* __restrict__ x, const float* __restrict__ w_in, const float* __restrict__ b_in,
    const u16* __restrict__ bpt, const u16* __restrict__ wsd,
    u16* __restrict__ fsum_out)
{
  int bt = blockIdx.x;
  int tid = threadIdx.x;
  int lane = tid & 63, wid = tid >> 6;
  int lr = lane & 15, lq = lane >> 4;
  __shared__ float xv[NNODE][4];
  __shared__ __align__(16) short sh0[32*136];
  __shared__ __align__(16) short hmT[128*40];
  __shared__ __align__(16) short alb[4*32*40];
  __shared__ float sd[2][NNODE][4];
  __shared__ float sm[4][NNODE];
  short8 bp[4][2];
  #pragma unroll
  for (int ks=0;ks<4;++ks)
    #pragma unroll
    for (int ct=0;ct<2;++ct)
      bp[ks][ct] = *(const short8*)(bpt + (size_t)(wid*32+ct*16+lr)*128 + ks*32 + lq*8);
  int ii = tid & 127, nn0 = tid >> 7;
  float w0 = w_in[ii], w1 = w_in[128+ii], w2 = w_in[256+ii], bi = b_in[ii];
  if (tid < NNODE*3) xv[tid/3][tid%3] = x[(size_t)bt*63 + tid];
  __syncthreads();
  #pragma unroll
  for (int n = 0; n < 32; n += 2) {
    int nr = n + nn0;
    float v = 0.f;
    if (nr < NNODE)
      v = fmaxf(bi + xv[nr][0]*w0 + xv[nr][1]*w1 + xv[nr][2]*w2, 0.f);
    sh0[nr*136 + ii] = (short)f2bf(v);
  }
  __syncthreads();
  {
    f32x4 g00={},g01={},g10={},g11={},s0v={},s1v={};
    #pragma unroll
    for (int ks=0;ks<4;++ks){
      short8 a0 = *(const short8*)&sh0[(lr   )*136 + ks*32 + lq*8];
      short8 a1 = *(const short8*)&sh0[(16+lr)*136 + ks*32 + lq*8];
      g00 = __builtin_amdgcn_mfma_f32_16x16x32_bf16(a0, bp[ks][0], g00, 0,0,0);
      g01 = __builtin_amdgcn_mfma_f32_16x16x32_bf16(a0, bp[ks][1], g01, 0,0,0);
      g10 = __builtin_amdgcn_mfma_f32_16x16x32_bf16(a1, bp[ks][0], g10, 0,0,0);
      g11 = __builtin_amdgcn_mfma_f32_16x16x32_bf16(a1, bp[ks][1], g11, 0,0,0);
      if (wid == 0) {
        short8 wb = *(const short8*)(wsd + (size_t)lr*128 + ks*32 + lq*8);
        s0v = __builtin_amdgcn_mfma_f32_16x16x32_bf16(a0, wb, s0v, 0,0,0);
        s1v = __builtin_amdgcn_mfma_f32_16x16x32_bf16(a1, wb, s1v, 0,0,0);
      }
    }
    f32x4 gg[2][2] = {{g00,g01},{g10,g11}};
    #pragma unroll
    for (int mt=0;mt<2;++mt)
      #pragma unroll
      for (int ct=0;ct<2;++ct){
        int col = wid*32 + ct*16 + lr;
        int row0 = mt*16 + lq*4;
        u32 wv0 = pk2bf(gg[mt][ct][0], gg[mt][ct][1]);
        u32 wv1 = pk2bf(gg[mt][ct][2], gg[mt][ct][3]);
        *(uint2*)&hmT[col*40 + row0] = make_uint2(wv0,wv1);
      }
    if (wid == 0 && lr < 8) {
      int which = lr >> 2, h = lr & 3;
      #pragma unroll
      for (int r=0;r<4;++r){
        int n0_ = lq*4 + r, n1_ = 16 + lq*4 + r;
        if (n0_ < NNODE) sd[which][n0_][h] = s0v[r];
        if (n1_ < NNODE) sd[which][n1_][h] = s1v[r];
      }
    }
  }
  __syncthreads();
  if (tid < 84) {
    int i = tid >> 2, h = tid & 3;
    float sv = sd[0][i][h], m = -1e30f;
    #pragma unroll
    for (int j=0;j<NNODE;++j){
      float e = sv + sd[1][j][h];
      e = e>=0.f ? e : 0.2f*e;
      m = fmaxf(m,e);
    }
    sm[h][i] = m;
  }
  __syncthreads();
  for (int idx = tid; idx < 84*32; idx += 256) {
    int j = idx & 31, ih = idx >> 5;
    int i = ih >> 2, h = ih & 3;
    float m = sm[h][i];
    float ex = 0.f;
    if (j < NNODE){
      float e = sd[0][i][h] + sd[1][j][h];
      e = e>=0.f ? e : 0.2f*e;
      ex = __expf(e - m);
    }
    alb[(h*32+i)*40 + j] = (short)f2bf(ex);
    float s = ex;
    #pragma unroll
    for (int off=1; off<32; off<<=1) s += __shfl_xor(s, off);
    if (j == 0) sm[h][i] = 1.f/s;
  }
  __syncthreads();
  {
    int h = wid;
    short8 a0 = *(const short8*)&alb[(h*32 + lr     )*40 + lq*8];
    short8 a1 = *(const short8*)&alb[(h*32 + 16 + lr)*40 + lq*8];
    short8 b0 = *(const short8*)&hmT[(h*32 + lr     )*40 + lq*8];
    short8 b1 = *(const short8*)&hmT[(h*32 + 16 + lr)*40 + lq*8];
    f32x4 c00={},c01={},c10={},c11={};
    c00 = __builtin_amdgcn_mfma_f32_16x16x32_bf16(a0,b0,c00,0,0,0);
    c01 = __builtin_amdgcn_mfma_f32_16x16x32_bf16(a0,b1,c01,0,0,0);
    c10 = __builtin_amdgcn_mfma_f32_16x16x32_bf16(a1,b0,c10,0,0,0);
    c11 = __builtin_amdgcn_mfma_f32_16x16x32_bf16(a1,b1,c11,0,0,0);
    f32x4 cc[2][2] = {{c00,c01},{c10,c11}};
    #pragma unroll
    for (int ct=0; ct<2; ++ct){
      int col = h*32 + ct*16 + lr;
      float s = 0.f;
      #pragma unroll
      for (int mt=0; mt<2; ++mt)
        #pragma unroll
        for (int r=0;r<4;++r){
          int n = mt*16 + lq*4 + r;
          if (n < NNODE)
            s += fmaxf(bf2f((u16)sh0[n*136+col]) + cc[mt][ct][r]*sm[h][n], 0.f);
        }
      s += __shfl_xor(s, 16);
      s += __shfl_xor(s, 32);
      if (lq == 0) fsum_out[(size_t)bt*128 + col] = f2bf(s*(1.f/21.f));
    }
  }
}

// ---------- bf16 MFMA GEMM, 128x128 tile, BK=64, XOR-swizzled LDS ----------
template<int ACC, int BIAS, int RELU, int SM>
__global__ __launch_bounds__(256) void gemm_bf16_kernel(
    const u16* __restrict__ A, const u16* __restrict__ BT, const float* __restrict__ bias,
    float* __restrict__ C, u16* __restrict__ C2,
    int M, int N, int K, int lda)
{
  __shared__ __align__(16) short Asl[8192];
  __shared__ __align__(16) short Bsl[8192];
  int tid = threadIdx.x;
  int lane = tid & 63, wid = tid >> 6;
  int wm = wid >> 1, wn = wid & 1;
  int row0 = blockIdx.y*128, col0 = blockIdx.x*128;
  const u16* Ab = A  + (size_t)row0*lda;
  const u16* Bb = BT + (size_t)col0*K;
  f32x4 acc[4][4] = {};
  int lrow = lane & 15, lk = (lane>>4)*8;
  for (int k0 = 0; k0 < K; k0 += 64) {
    #pragma unroll
    for (int is=0; is<4; ++is){
      int li = is*256 + tid;
      int row = li >> 3;
      int c8  = (li & 7) ^ (row & 7);
      gload16(Ab + (size_t)row*lda + k0 + c8*8, (u16*)Asl + ((is<<8)+(wid<<6))*8);
      gload16(Bb + (size_t)row*K   + k0 + c8*8, (u16*)Bsl + ((is<<8)+(wid<<6))*8);
    }
    __syncthreads();
    #pragma unroll
    for (int ksub=0; ksub<2; ++ksub){
      int slot = (ksub*32 + lk) >> 3;
      short8 a[4], b[4];
      #pragma unroll
      for (int i=0;i<4;++i){ int rr=wm*64+i*16+lrow; a[i]=*(const short8*)&Asl[rr*64+((slot^(rr&7))<<3)]; }
      #pragma unroll
      for (int j=0;j<4;++j){ int rr=wn*64+j*16+lrow; b[j]=*(const short8*)&Bsl[rr*64+((slot^(rr&7))<<3)]; }
      #pragma unroll
      for (int i=0;i<4;++i)
        #pragma unroll
        for (int j=0;j<4;++j)
          acc[i][j] = __builtin_amdgcn_mfma_f32_16x16x32_bf16(a[i], b[j], acc[i][j], 0, 0, 0);
    }
    __syncthreads();
  }
  #pragma unroll
  for (int i=0;i<4;++i) {
    int row = row0 + wm*64 + i*16 + (lane>>4)*4;
    #pragma unroll
    for (int j=0;j<4;++j) {
      int col = col0 + wn*64 + j*16 + (lane&15);
      if (col < N) {
        float bv = BIAS ? bias[col] : 0.f;
        #pragma unroll
        for (int r=0;r<4;++r) {
          float v = acc[i][j][r] + bv;
          if (RELU) v = fmaxf(v, 0.f);
          size_t o = (size_t)(row+r)*N + col;
          if (ACC)           C[o] += v;
          else if (SM == 0)  C[o]  = v;
          else               C2[o] = f2bf(v);
        }
      }
    }
  }
}

// ---------- bf16 MFMA GEMM, BM=64 x BN=128, BK=64 (occupancy tile) ----------
// POOL: per-block column partials of FINAL value (ACC-updated) * 1/256 -> pool
template<int ACC, int BIAS, int RELU, int SM, int POOL>
__global__ __launch_bounds__(256) void gemm_bm64_kernel(
    const u16* __restrict__ A, const u16* __restrict__ BT, const float* __restrict__ bias,
    float* __restrict__ C, u16* __restrict__ C2, float* __restrict__ pool,
    int M, int N, int K, int lda)
{
  __shared__ __align__(16) short Asl[4096];    // [64][64]
  __shared__ __align__(16) short Bsl[8192];    // [128][64]
  int tid = threadIdx.x;
  int lane = tid & 63, wid = tid >> 6;
  int wm = wid >> 1, wn = wid & 1;
  int row0 = blockIdx.y*64, col0 = blockIdx.x*128;
  const u16* Ab = A  + (size_t)row0*lda;
  const u16* Bb = BT + (size_t)col0*K;
  f32x4 acc[2][4] = {};
  int lrow = lane & 15, lq = lane >> 4, lk = lq*8;
  for (int k0 = 0; k0 < K; k0 += 64) {
    #pragma unroll
    for (int is=0; is<2; ++is){
      int li = is*256 + tid;
      int row = li >> 3;
      int c8  = (li & 7) ^ (row & 7);
      gload16(Ab + (size_t)row*lda + k0 + c8*8, (u16*)Asl + ((is<<8)+(wid<<6))*8);
    }
    #pragma unroll
    for (int is=0; is<4; ++is){
      int li = is*256 + tid;
      int row = li >> 3;
      int c8  = (li & 7) ^ (row & 7);
      gload16(Bb + (size_t)row*K + k0 + c8*8, (u16*)Bsl + ((is<<8)+(wid<<6))*8);
    }
    __syncthreads();
    #pragma unroll
    for (int ksub=0; ksub<2; ++ksub){
      int slot = (ksub*32 + lk) >> 3;
      short8 a[2], b[4];
      #pragma unroll
      for (int i=0;i<2;++i){ int rr=wm*32+i*16+lrow; a[i]=*(const short8*)&Asl[rr*64+((slot^(rr&7))<<3)]; }
      #pragma unroll
      for (int j=0;j<4;++j){ int rr=wn*64+j*16+lrow; b[j]=*(const short8*)&Bsl[rr*64+((slot^(rr&7))<<3)]; }
      #pragma unroll
      for (int i=0;i<2;++i)
        #pragma unroll
        for (int j=0;j<4;++j)
          acc[i][j] = __builtin_amdgcn_mfma_f32_16x16x32_bf16(a[i], b[j], acc[i][j], 0, 0, 0);
    }
    __syncthreads();
  }
  float colsum[4] = {0.f,0.f,0.f,0.f};
  #pragma unroll
  for (int i=0;i<2;++i) {
    int row = row0 + wm*32 + i*16 + lq*4;
    #pragma unroll
    for (int j=0;j<4;++j) {
      int col = col0 + wn*64 + j*16 + lrow;
      if (col < N) {
        float bv = BIAS ? bias[col] : 0.f;
        #pragma unroll
        for (int r=0;r<4;++r) {
          float v = acc[i][j][r] + bv;
          if (RELU) v = fmaxf(v, 0.f);
          size_t o = (size_t)(row+r)*N + col;
          float fv;
          if (ACC) { fv = C[o] + v; C[o] = fv; }
          else     { fv = v;
                     if (SM == 0)  C[o]  = v;
                     else          C2[o] = f2bf(v); }
          if (POOL) colsum[j] += fv;
        }
      }
    }
  }
  if (POOL) {
    float* red = (float*)Asl;
    #pragma unroll
    for (int j=0;j<4;++j) red[tid*4+j] = colsum[j];
    __syncthreads();
    if (tid < 128) {
      int wn_ = tid >> 6, j_ = (tid >> 4) & 3, l15 = tid & 15;
      float s = 0.f;
      #pragma unroll
      for (int wm_=0;wm_<2;++wm_)
        #pragma unroll
        for (int g=0;g<4;++g)
          s += red[(((wm_*2+wn_)*64) + g*16 + l15)*4 + j_];
      pool[(size_t)blockIdx.y*256 + blockIdx.x*128 + tid] = s * (1.f/256.f);
    }
  }
}

// ---------- x_proj GEMM: C[M][128], col-block d = dir; K=512, no padding ----------
__global__ __launch_bounds__(256) void gemm_xproj_kernel(
    const u16* __restrict__ A, const u16* __restrict__ BT, float* __restrict__ C)
{
  __shared__ __align__(16) short Asl[4096];    // [64][64]
  __shared__ __align__(16) short Bsl[4096];    // [64][64]
  int tid = threadIdx.x;
  int lane = tid & 63, wid = tid >> 6;
  int lrow = lane & 15, lq = lane >> 4, lk = lq*8;
  int d = blockIdx.x, row0 = blockIdx.y*64;
  const u16* Ab = A  + (size_t)row0*1024 + d*512;
  const u16* Bb = BT + (size_t)d*32768;
  f32x4 acc[4] = {};
  for (int k0 = 0; k0 < 512; k0 += 64) {
    #pragma unroll
    for (int is=0; is<2; ++is){
      int li = is*256 + tid;
      int row = li >> 3;
      int c8  = (li & 7) ^ (row & 7);
      gload16(Ab + (size_t)row*1024 + k0 + c8*8, (u16*)Asl + ((is<<8)+(wid<<6))*8);
      gload16(Bb + (size_t)row*512  + k0 + c8*8, (u16*)Bsl + ((is<<8)+(wid<<6))*8);
    }
    __syncthreads();
    #pragma unroll
    for (int ksub=0; ksub<2; ++ksub){
      int slot = (ksub*32 + lk) >> 3;
      int arr = wid*16 + lrow;
      short8 av = *(const short8*)&Asl[arr*64 + ((slot^(arr&7))<<3)];
      #pragma unroll
      for (int j=0;j<4;++j){
        int brr = j*16 + lrow;
        short8 bv = *(const short8*)&Bsl[brr*64 + ((slot^(brr&7))<<3)];
        acc[j] = __builtin_amdgcn_mfma_f32_16x16x32_bf16(av, bv, acc[j], 0, 0, 0);
      }
    }
    __syncthreads();
  }
  #pragma unroll
  for (int j=0;j<4;++j){
    int col = d*64 + j*16 + lrow;
    #pragma unroll
    for (int r=0;r<4;++r){
      int row = row0 + wid*16 + lq*4 + r;
      C[(size_t)row*128 + col] = acc[j][r];
    }
  }
}

// ---------- LayerNorm -> bf16 ----------
__global__ __launch_bounds__(256) void ln_kernel(const float* __restrict__ x,
    const float* __restrict__ w, u16* __restrict__ o)
{
  int row = blockIdx.x*4 + (threadIdx.x>>6);
  int lane = threadIdx.x & 63;
  float4 v = *(const float4*)(x + (size_t)row*DMODEL + lane*4);
  float s = v.x+v.y+v.z+v.w;
  #pragma unroll
  for (int off=32;off>=1;off>>=1) s += __shfl_xor(s, off);
  float mu = s * (1.f/256.f);
  float d0=v.x-mu, d1=v.y-mu, d2=v.z-mu, d3=v.w-mu;
  float q = d0*d0+d1*d1+d2*d2+d3*d3;
  #pragma unroll
  for (int off=32;off>=1;off>>=1) q += __shfl_xor(q, off);
  float inv = 1.f/sqrtf(q*(1.f/256.f) + 1e-5f);
  float4 wv = *(const float4*)(w + lane*4);
  uint2 pk; pk.x = pk2bf(d0*inv*wv.x, d1*inv*wv.y); pk.y = pk2bf(d2*inv*wv.z, d3*inv*wv.w);
  *(uint2*)(o + (size_t)row*DMODEL + lane*4) = pk;
}

// ---------- depthwise conv + silu, 8-channel vectorized, both dirs ----------
__global__ __launch_bounds__(256) void conv_kernel(const u16* __restrict__ xz,
    const float* __restrict__ cw, const float* __restrict__ cb,
    u16* __restrict__ ucv)
{
  int idx = blockIdx.x*256 + threadIdx.x;          // BT*128
  int du8 = idx & 127, dir = du8 >> 6, d8 = (du8 & 63) << 3;
  int bt = idx >> 7, t = bt & 255;
  const u16* up = xz + (size_t)(bt - t)*2048 + dir*512 + d8;
  float w[8][4];
  #pragma unroll
  for (int j=0;j<8;++j){
    float4 wv = *(const float4*)(cw + (size_t)dir*2048 + (d8+j)*4);
    w[j][0]=wv.x; w[j][1]=wv.y; w[j][2]=wv.z; w[j][3]=wv.w;
  }
  float s[8];
  float4 cb0 = *(const float4*)(cb + dir*512 + d8);
  float4 cb1 = *(const float4*)(cb + dir*512 + d8 + 4);
  s[0]=cb0.x; s[1]=cb0.y; s[2]=cb0.z; s[3]=cb0.w;
  s[4]=cb1.x; s[5]=cb1.y; s[6]=cb1.z; s[7]=cb1.w;
  if (dir == 0) {
    #pragma unroll
    for (int k=0;k<4;++k){
      int tk = t-3+k;
      if (tk >= 0){
        short8 uv = *(const short8*)(up + (size_t)tk*2048);
        #pragma unroll
        for (int j=0;j<8;++j) s[j] += w[j][k]*bf2f((u16)uv[j]);
      }
    }
  } else {
    #pragma unroll
    for (int kk=0;kk<4;++kk){
      int tk = t+kk;
      if (tk < TT){
        short8 uv = *(const short8*)(up + (size_t)tk*2048);
        #pragma unroll
        for (int j=0;j<8;++j) s[j] += w[j][3-kk]*bf2f((u16)uv[j]);
      }
    }
  }
  short8 o;
  #pragma unroll
  for (int j=0;j<8;++j) o[j] = (short)f2bf(siluf(s[j]));
  *(short8*)(ucv + (size_t)bt*1024 + dir*512 + d8) = o;
}

// ---------- chunked selective scan, pow-chain dA (guarded) ----------
// grid (64 b, {7|8} c, 4 = d*2 + half)
template<int FINAL>
__global__ __launch_bounds__(256) void scan_phase_kernel(
    const u16* __restrict__ ucv, const float* __restrict__ xd, const u16* __restrict__ xz,
    const float* __restrict__ dtw, const float* __restrict__ dtb,
    const float* __restrict__ alog, const float* __restrict__ dvec,
    const u16* __restrict__ hend_r, const float* __restrict__ sdt_r,
    float* __restrict__ sdt_w, u16* __restrict__ hend_w,
    u16* __restrict__ yout)
{
  int b = blockIdx.x, c = blockIdx.y, gz = blockIdx.z;
  int d = gz >> 1;
  int tid = threadIdx.x;
  int dd = ((gz & 1) << 8) + tid;
  float wdt[16], Av[16], h[16];
  #pragma unroll
  for (int s=0;s<16;++s){
    wdt[s] = dtw[d*8192 + s*512 + dd];
    Av[s]  = -__expf(alog[d*8192 + dd*16 + s]);
    h[s]   = 0.f;
  }
  float bdt = dtb[d*512 + dd];
  bool powok = true;
  #pragma unroll
  for (int s=0;s<16;++s) powok = powok && (fabsf(Av[s] + (float)(s+1)) < 1e-5f*(float)(s+1));
  __shared__ float sxd[32][48];
  if (FINAL) {
    for (int i = tid; i < 1536; i += 256){
      int q = i/48, r = i - q*48;
      int p = (c<<5)+q, t = d ? 255-p : p;
      sxd[q][r] = xd[((size_t)b*TT + t)*128 + d*64 + r];
    }
  } else {
    for (int i = tid; i < 1024; i += 256){
      int q = i>>5, r = i&31;
      int p = (c<<5)+q, t = d ? 255-p : p;
      sxd[q][r] = xd[((size_t)b*TT + t)*128 + d*64 + r];
    }
  }
  if (FINAL) {
    if (powok) {
      for (int cp=0; cp<c; ++cp){
        size_t cbase = (((size_t)b*8+cp)*2+d)*512 + dd;
        float S = sdt_r[cbase];
        float e1 = __expf(-S);
        short8 h0v = *(const short8*)(hend_r + cbase*16);
        short8 h1v = *(const short8*)(hend_r + cbase*16 + 8);
        float pw = e1;
        #pragma unroll
        for (int s=0;s<8;++s){ h[s] = fmaf(pw, h[s], bf2f((u16)h0v[s])); pw *= e1; }
        #pragma unroll
        for (int s=0;s<8;++s){ h[s+8] = fmaf(pw, h[s+8], bf2f((u16)h1v[s])); pw *= e1; }
      }
    } else {
      for (int cp=0; cp<c; ++cp){
        size_t cbase = (((size_t)b*8+cp)*2+d)*512 + dd;
        float S = sdt_r[cbase];
        short8 h0v = *(const short8*)(hend_r + cbase*16);
        short8 h1v = *(const short8*)(hend_r + cbase*16 + 8);
        #pragma unroll
        for (int s=0;s<8;++s)  h[s]   = fmaf(__expf(Av[s]*S),   h[s],   bf2f((u16)h0v[s]));
        #pragma unroll
        for (int s=0;s<8;++s)  h[s+8] = fmaf(__expf(Av[s+8]*S), h[s+8], bf2f((u16)h1v[s]));
      }
    }
  }
  __syncthreads();
  float S = 0.f;
  float Dv = FINAL ? dvec[d*512 + dd] : 0.f;
  const u16* ub = ucv + d*512 + dd;
  const u16* zb = xz + 1024 + d*512 + dd;
  u16* yb = yout + d*512 + dd;
  auto qloop = [&](auto icpow){
    constexpr int POW = decltype(icpow)::v;
    #pragma unroll 4
    for (int q=0;q<32;++q) {
      int p = (c<<5)+q, t = d ? 255-p : p;
      size_t row = (size_t)b*TT + t;
      float uc = bf2f(ub[row*1024]);
      float zc = FINAL ? bf2f(zb[row*2048]) : 0.f;
      const float* sr = sxd[q];
      float p0=0.f,p1=0.f,p2=0.f,p3=0.f;
      #pragma unroll
      for (int r=0;r<16;r+=4){
        p0 = fmaf(sr[r+0],wdt[r+0],p0);
        p1 = fmaf(sr[r+1],wdt[r+1],p1);
        p2 = fmaf(sr[r+2],wdt[r+2],p2);
        p3 = fmaf(sr[r+3],wdt[r+3],p3);
      }
      float dtp = bdt + ((p0+p1)+(p2+p3));
      float dt = fmaxf(dtp,0.f) + __logf(1.f + __expf(-fabsf(dtp)));
      float dtu = dt*uc;
      if (!FINAL) S += dt;
      float y0=0.f, y1=0.f;
      if (POW) {
        float rr = __expf(-dt);
        float pw = rr;
        #pragma unroll
        for (int s=0;s<16;++s){
          h[s] = fmaf(pw, h[s], dtu*sr[16+s]);
          if (FINAL) y0 = fmaf(h[s], sr[32+s], y0);
          pw *= rr;
        }
      } else {
        #pragma unroll
        for (int s=0;s<16;s+=2){
          float dA0 = __expf(dt*Av[s]);
          float dA1 = __expf(dt*Av[s+1]);
          h[s]   = fmaf(dA0, h[s],   dtu*sr[16+s]);
          h[s+1] = fmaf(dA1, h[s+1], dtu*sr[16+s+1]);
          if (FINAL){ y0 = fmaf(h[s],sr[32+s],y0); y1 = fmaf(h[s+1],sr[32+s+1],y1); }
        }
      }
      if (FINAL){
        float yv = (y0+y1) + uc*Dv;
        float sg = zc / (1.f + __expf(-zc));
        yb[row*2048] = f2bf(yv*sg);
      }
    }
  };
  if (powok) qloop(IC<1>{}); else qloop(IC<0>{});
  if (!FINAL){
    size_t co = (((size_t)b*8+c)*2+d)*512 + dd;
    sdt_w[co] = S;
    short8 o0, o1;
    #pragma unroll
    for (int s=0;s<8;++s){ o0[s] = (short)f2bf(h[s]); o1[s] = (short)f2bf(h[s+8]); }
    *(short8*)(hend_w + co*16)     = o0;
    *(short8*)(hend_w + co*16 + 8) = o1;
  }
}

// ---------- emb: temporal mean (from out_proj pool partials) + sign GEMV ----------
__global__ __launch_bounds__(256) void emb_kernel(const float* __restrict__ part_m,
    const float* __restrict__ wsgn, const float* __restrict__ bsgn,
    float* __restrict__ embw, float* __restrict__ out)
{
  int b = blockIdx.x, tid = threadIdx.x;
  __shared__ float mt[256];
  mt[tid] = part_m[(size_t)(4*b)*256 + tid] + part_m[(size_t)(4*b+1)*256 + tid]
          + part_m[(size_t)(4*b+2)*256 + tid] + part_m[(size_t)(4*b+3)*256 + tid];
  __syncthreads();
  float acc = bsgn[tid];
  for (int i=0;i<DMODEL;++i) acc += mt[i]*wsgn[i*DMODEL + tid];
  embw[b*DMODEL+tid] = acc;
  out[128000 + b*DMODEL + tid] = acc;
}

// ---------- head+sims fused: grid (64, 5); qt<4 sign logits, qt==4 sims ----------
__global__ __launch_bounds__(256) void head_kernel(const float* __restrict__ embw,
    const float* __restrict__ protos, const float* __restrict__ part,
    const float* __restrict__ phs, const float* __restrict__ ploc,
    const float* __restrict__ pmov, const float* __restrict__ pori,
    float* __restrict__ out)
{
  int b = blockIdx.x, qt = blockIdx.y, tid = threadIdx.x;
  __shared__ __align__(16) float e[256];
  __shared__ float red[4];
  if (qt == 4) {
    e[tid] = part[(size_t)(4*b)*256 + tid] + part[(size_t)(4*b+1)*256 + tid]
           + part[(size_t)(4*b+2)*256 + tid] + part[(size_t)(4*b+3)*256 + tid];
    __syncthreads();
    if (tid < 4) {
      float ss = 0.f;
      for (int i=0;i<64;++i){ float q = e[tid*64+i]; ss += q*q; }
      red[tid] = 1.f/(sqrtf(ss)+1e-8f);
    }
    __syncthreads();
    if (tid < 88) {
      int k, pi; const float* P; size_t off; int npk;
      if (tid < 40)      { k=0; pi=tid;    P=phs;  off=144384; npk=40; }
      else if (tid < 60) { k=1; pi=tid-40; P=ploc; off=146944; npk=20; }
      else if (tid < 80) { k=2; pi=tid-60; P=pmov; off=148224; npk=20; }
      else               { k=3; pi=tid-80; P=pori; off=149504; npk=8;  }
      float dot=0.f, ps=0.f;
      for (int i=0;i<64;++i){ float pv = P[pi*64+i]; dot += pv*e[k*64+i]; ps += pv*pv; }
      out[off + (size_t)b*npk + pi] = dot*red[k]/(sqrtf(ps)+1e-8f)*(1.f/0.07f);
    }
    return;
  }
  float acc = embw[b*DMODEL + tid];
  e[tid] = acc;
  __syncthreads();
  float v = acc*acc;
  #pragma unroll
  for (int off=32;off>=1;off>>=1) v += __shfl_xor(v, off);
  if ((tid&63)==0) red[tid>>6] = v;
  __syncthreads();
  float esc = 1.f/(sqrtf(red[0]+red[1]+red[2]+red[3]) + 1e-8f);
  int pend = qt*500 + 500;
  for (int p = qt*500 + tid; p < pend; p += 256) {
    const float* pr = protos + (size_t)p*256;
    float dot=0.f, ps=0.f;
    for (int i=0;i<256;i+=4) {
      float4 pv = *(const float4*)(pr+i);
      float4 ev = *(const float4*)(e+i);
      dot += pv.x*ev.x + pv.y*ev.y + pv.z*ev.z + pv.w*ev.w;
      ps  += pv.x*pv.x + pv.y*pv.y + pv.z*pv.z + pv.w*pv.w;
    }
    out[(size_t)b*NSIGNS + p] = dot*esc/(sqrtf(ps)+1e-8f)*(1.f/0.07f);
  }
}

extern "C" void kernel_launch(void* const* d_in, const int* in_sizes, int n_in,
                              void* d_out, int out_size, void* d_ws, size_t ws_size,
                              hipStream_t stream) {
  const float* x         = (const float*)d_in[0];
  const float* w_in      = (const float*)d_in[1];
  const float* b_in      = (const float*)d_in[2];
  const float* w_gat     = (const float*)d_in[3];
  const float* a_src     = (const float*)d_in[4];
  const float* a_dst     = (const float*)d_in[5];
  const float* w_out     = (const float*)d_in[6];
  const float* b_out     = (const float*)d_in[7];
  const float* pdm_w     = (const float*)d_in[8];
  const float* pdm_b     = (const float*)d_in[9];
  const float* w_fuse    = (const float*)d_in[10];
  const float* b_fuse    = (const float*)d_in[11];
  const float* ln_w      = (const float*)d_in[12];
  const float* in_proj   = (const float*)d_in[13];
  const float* conv_w    = (const float*)d_in[14];
  const float* conv_b    = (const float*)d_in[15];
  const float* x_proj    = (const float*)d_in[16];
  const float* dt_w      = (const float*)d_in[17];
  const float* dt_b      = (const float*)d_in[18];
  const float* A_log     = (const float*)d_in[19];
  const float* Dvec      = (const float*)d_in[20];
  const float* out_proj  = (const float*)d_in[21];
  const float* w_sign    = (const float*)d_in[22];
  const float* b_sign    = (const float*)d_in[23];
  const float* protos    = (const float*)d_in[24];
  const float* phs       = (const float*)d_in[25];
  const float* ploc      = (const float*)d_in[26];
  const float* pmov      = (const float*)d_in[27];
  const float* pori      = (const float*)d_in[28];
  float* out = (float*)d_out;

  // ---- ws layout ----
  float* wsf = (float*)d_ws;
  const size_t f_xx    = 0;                          // 16384*256
  const size_t f_xdbl  = f_xx    + 4194304;          // 16384*128
  const size_t f_part  = f_xdbl  + 2097152;          // 256*256  (comps pool)
  const size_t f_mpart = f_part  + 65536;            // 256*256  (final xx mean pool)
  const size_t f_emb   = f_mpart + 65536;            // 64*256
  const size_t f_end   = f_emb   + 16384;
  u16* wsu = (u16*)(wsf + f_end);
  const size_t u_xn    = 0;                          // 16384*256
  const size_t u_xz    = u_xn   + 4194304;           // 16384*2048 [u0 u1 z0 z1]; y -> u slots
  const size_t u_ucv   = u_xz   + 33554432;          // 16384*1024
  const size_t u_fsum  = u_ucv  + 16777216;          // 16384*128
  const size_t u_spat  = u_fsum + 2097152;           // 16384*256
  const size_t u_comps = u_spat + 4194304;           // 16384*256
  const size_t u_w     = u_comps+ 4194304;           // weights
  u16* wiT = wsu + u_w;
  u16* woT = wiT + 2097152;
  u16* wxT = woT + 1048576;
  u16* wA  = wxT + 524288;
  u16* wB  = wA  + 32768;
  u16* wF  = wB  + 65536;
  u16* wBp = wF  + 65536;
  u16* wSd = wBp + 16384;              // [16][128] folded sd weights
  // scan scratch aliases fsum/spat/comps (dead during SSM loop)
  u16*   hstate = wsu + u_fsum;                      // 64*8*2*512*16 u16 = 16MB
  float* sdt    = (float*)(wsu + u_fsum + 8388608);  // 64*8*2*512 f32 = 2MB

  transpose_w_kernel<<<945, 256, 0, stream>>>(in_proj, out_proj, x_proj, w_out, pdm_w, w_fuse, w_gat, a_src, a_dst, wsu + u_w);
  agan_kernel<<<BTT, 256, 0, stream>>>(x, w_in, b_in, wBp, wSd, wsu + u_fsum);
  gemm_bm64_kernel<0,1,0,1,0><<<dim3(2,256), 256, 0, stream>>>(wsu+u_fsum, wA, b_out, nullptr, wsu+u_spat, nullptr, BTT, 256, 128, 128);
  gemm_bm64_kernel<0,1,1,1,1><<<dim3(2,256), 256, 0, stream>>>(wsu+u_spat, wB, pdm_b, nullptr, wsu+u_comps, wsf+f_part, BTT, 256, 256, 256);
  gemm_bm64_kernel<0,1,0,0,0><<<dim3(2,256), 256, 0, stream>>>(wsu+u_comps, wF, b_fuse, wsf+f_xx, nullptr, nullptr, BTT, 256, 256, 256);

  for (int l = 0; l < 4; ++l) {
    ln_kernel<<<BTT/4, 256, 0, stream>>>(wsf+f_xx, ln_w + l*DMODEL, wsu+u_xn);
    gemm_bf16_kernel<0,0,0,1><<<dim3(16,128), 256, 0, stream>>>(wsu+u_xn, wiT + (size_t)l*524288,
        nullptr, nullptr, wsu+u_xz, BTT, 2048, 256, 256);
    conv_kernel<<<BTT*128/256, 256, 0, stream>>>(wsu+u_xz, conv_w + (size_t)l*4096,
        conv_b + (size_t)l*1024, wsu+u_ucv);
    gemm_xproj_kernel<<<dim3(2,256), 256, 0, stream>>>(wsu+u_ucv, wxT + (size_t)l*131072, wsf+f_xdbl);
    scan_phase_kernel<0><<<dim3(64,7,4), 256, 0, stream>>>(wsu+u_ucv, wsf+f_xdbl, nullptr,
        dt_w + (size_t)l*16384, dt_b + (size_t)l*1024,
        A_log + (size_t)l*16384, nullptr,
        nullptr, nullptr, sdt, hstate, nullptr);
    scan_phase_kernel<1><<<dim3(64,8,4), 256, 0, stream>>>(wsu+u_ucv, wsf+f_xdbl, wsu+u_xz,
        dt_w + (size_t)l*16384, dt_b + (size_t)l*1024,
        A_log + (size_t)l*16384, Dvec + (size_t)l*1024,
        hstate, sdt, nullptr, nullptr, wsu+u_xz);
    if (l < 3)
      gemm_bm64_kernel<1,0,0,0,0><<<dim3(2,256), 256, 0, stream>>>(wsu+u_xz, woT + (size_t)l*262144,
          nullptr, wsf+f_xx, nullptr, nullptr, BTT, 256, 1024, 2048);
    else
      gemm_bm64_kernel<1,0,0,0,1><<<dim3(2,256), 256, 0, stream>>>(wsu+u_xz, woT + (size_t)l*262144,
          nullptr, wsf+f_xx, nullptr, wsf+f_mpart, BTT, 256, 1024, 2048);
  }

  emb_kernel<<<64, 256, 0, stream>>>(wsf+f_mpart, w_sign, b_sign, wsf+f_emb, out);
  head_kernel<<<dim3(64,5), 256, 0, stream>>>(wsf+f_emb, protos, wsf+f_part, phs, ploc, pmov, pori, out);
  (void)in_sizes; (void)n_in; (void)out_size; (void)ws_size;
}

// Round 17
// 1045.546 us; speedup vs baseline: 1.1843x; 1.0647x over previous
//
#include <hip/hip_runtime.h>
#include <hip/hip_bf16.h>
#include <math.h>

#define BB 64
#define TT 256
#define NNODE 21
#define HID 128
#define DMODEL 256
#define DINNER 512
#define NSIGNS 2000
#define BTT (BB*TT)   // 16384

typedef unsigned short u16;
typedef unsigned int u32;
typedef __attribute__((ext_vector_type(8))) short short8;
typedef __attribute__((ext_vector_type(4))) float f32x4;

template<int V> struct IC { static constexpr int v = V; };

__device__ __forceinline__ float siluf(float x){ return x/(1.f+expf(-x)); }
__device__ __forceinline__ u16 f2bf(float x){ __hip_bfloat16 h = __float2bfloat16(x); return *(u16*)&h; }
__device__ __forceinline__ u32 pk2bf(float a, float b){
  float2 f2; f2.x = a; f2.y = b;
  __hip_bfloat162 h2 = __float22bfloat162_rn(f2);
  return *(u32*)&h2;
}
__device__ __forceinline__ float bf2f(u16 u){ return __uint_as_float(((u32)u)<<16); }
__device__ __forceinline__ void gload16(const u16* g, u16* l){
  __builtin_amdgcn_global_load_lds((const __attribute__((address_space(1))) void*)g,
                                   (__attribute__((address_space(3))) void*)l, 16, 0, 0);
}

// ---------- tiled weight transpose -> bf16 [N][K] layouts ----------
// block 944: w_sdT[16][128] = folded attention weights (Bp_h · a_h)
__global__ __launch_bounds__(256) void transpose_w_kernel(
    const float* __restrict__ in_proj, const float* __restrict__ out_proj,
    const float* __restrict__ x_proj, const float* __restrict__ w_out,
    const float* __restrict__ pdm_w, const float* __restrict__ w_fuse,
    const float* __restrict__ w_gat, const float* __restrict__ a_src,
    const float* __restrict__ a_dst, u16* __restrict__ dst)
{
  __shared__ short tl[64*66];
  int bx = blockIdx.x, tid = threadIdx.x;
  if (bx == 944) {
    for (int j = tid; j < 2048; j += 256) {
      int c = j >> 7, i = j & 127;
      float v = 0.f;
      if (c < 8) {
        int which = c >> 2, h = c & 3;
        const float* a = (which ? a_dst : a_src) + h*32;
        const float* wg = w_gat + (size_t)h*4096 + i*32;
        #pragma unroll
        for (int o=0;o<32;++o) v += wg[o]*a[o];
      }
      dst[3850240 + j] = f2bf(v);
    }
    return;
  }
  const float* S = nullptr; size_t soff = 0; int lds = 0, Nsrc = 0;
  size_t doff = 0; int ldd = 0, Nout = 0;
  int tn = 0, tk = 0;
  if (bx < 512) {                       // in_projT
    int j = bx >> 5, tt = bx & 31;
    int l = j >> 2, d = j & 1, zh = (j >> 1) & 1;
    tn = tt >> 2; tk = tt & 3;
    S = in_proj; soff = ((size_t)(l*2+d)*256)*1024 + zh*512; lds = 1024; Nsrc = 512;
    doff = (size_t)l*524288 + (size_t)(zh*1024 + d*512)*256; ldd = 256; Nout = 512;
  } else if (bx < 768) {                // out_projT
    int j = (bx-512) >> 5, tt = (bx-512) & 31;
    int l = j >> 1, d = j & 1;
    tn = tt >> 3; tk = tt & 7;
    S = out_proj; soff = (size_t)(l*2+d)*512*256; lds = 256; Nsrc = 256;
    doff = 2097152 + (size_t)l*262144 + d*512; ldd = 1024; Nout = 256;
  } else if (bx < 896) {                // x_projT compact [l][2][64][512]
    int r = bx - 768;
    if (r >= 64) return;
    int j = r >> 3;
    int l = j >> 1, d = j & 1;
    tn = 0; tk = r & 7;
    S = x_proj; soff = (size_t)(l*2+d)*512*48; lds = 48; Nsrc = 48;
    doff = 3145728 + (size_t)l*131072 + (size_t)d*32768; ldd = 512; Nout = 64;
  } else if (bx < 904) {                // w_outT
    int tt = bx-896; tn = tt>>1; tk = tt&1;
    S = w_out; soff = 0; lds = 256; Nsrc = 256;
    doff = 3670016; ldd = 128; Nout = 256;
  } else if (bx < 920) {                // wbigT (pdm_w)
    int j = (bx-904)>>2, tt = (bx-904)&3;
    tn = 0; tk = tt;
    S = pdm_w; soff = (size_t)j*16384; lds = 64; Nsrc = 64;
    doff = 3702784 + (size_t)j*16384; ldd = 256; Nout = 64;
  } else if (bx < 936) {                // w_fuseT
    int tt = bx-920; tn = tt>>2; tk = tt&3;
    S = w_fuse; soff = 0; lds = 256; Nsrc = 256;
    doff = 3768320; ldd = 256; Nout = 256;
  } else {                              // BpT
    int j = (bx-936)>>1, tt = (bx-936)&1;
    tn = 0; tk = tt;
    S = w_gat; soff = (size_t)j*4096; lds = 32; Nsrc = 32;
    doff = 3833856 + (size_t)j*4096; ldd = 128; Nout = 32;
  }
  int n0 = tn*64, k0 = tk*64;
  #pragma unroll
  for (int i=0;i<16;++i){
    int kk = i*4 + (tid>>6), nn = tid&63;
    float v = (n0+nn < Nsrc) ? S[soff + (size_t)(k0+kk)*lds + n0+nn] : 0.f;
    tl[nn*66+kk] = (short)f2bf(v);
  }
  __syncthreads();
  #pragma unroll
  for (int i=0;i<16;++i){
    int nn = i*4 + (tid>>6), kk = tid&63;
    if (n0+nn < Nout) dst[doff + (size_t)(n0+nn)*ldd + k0+kk] = (u16)tl[nn*66+kk];
  }
}

// ---------- AGAN: hm/agg/sd via MFMA; monotone-max softmax (no serial max pass) ----------
__global__ __launch_bounds__(256) void agan_kernel(
    const float* __restrict__ x, const float* __restrict__ w_in, const float* __restrict__ b_in,
    const u16* __restrict__ bpt, const u16* __restrict__ wsd,
    u16* __restrict__ fsum_out)
{
  int bt = blockIdx.x;
  int tid = threadIdx.x;
  int lane = tid & 63, wid = tid >> 6;
  int lr = lane & 15, lq = lane >> 4;
  __shared__ float xv[NNODE][4];
  __shared__ __align__(16) short sh0[32*136];
  __shared__ __align__(16) short hmT[128*40];
  __shared__ __align__(16) short alb[4*32*40];
  __shared__ float sd[2][NNODE][4];
  __shared__ float sm[4][NNODE];
  __shared__ float smax[4];
  short8 bp[4][2];
  #pragma unroll
  for (int ks=0;ks<4;++ks)
    #pragma unroll
    for (int ct=0;ct<2;++ct)
      bp[ks][ct] = *(const short8*)(bpt + (size_t)(wid*32+ct*16+lr)*128 + ks*32 + lq*8);
  int ii = tid & 127, nn0 = tid >> 7;
  float w0 = w_in[ii], w1 = w_in[128+ii], w2 = w_in[256+ii], bi = b_in[ii];
  if (tid < NNODE*3) xv[tid/3][tid%3] = x[(size_t)bt*63 + tid];
  __syncthreads();
  #pragma unroll
  for (int n = 0; n < 32; n += 2) {
    int nr = n + nn0;
    float v = 0.f;
    if (nr < NNODE)
      v = fmaxf(bi + xv[nr][0]*w0 + xv[nr][1]*w1 + xv[nr][2]*w2, 0.f);
    sh0[nr*136 + ii] = (short)f2bf(v);
  }
  __syncthreads();
  {
    f32x4 g00={},g01={},g10={},g11={},s0v={},s1v={};
    #pragma unroll
    for (int ks=0;ks<4;++ks){
      short8 a0 = *(const short8*)&sh0[(lr   )*136 + ks*32 + lq*8];
      short8 a1 = *(const short8*)&sh0[(16+lr)*136 + ks*32 + lq*8];
      g00 = __builtin_amdgcn_mfma_f32_16x16x32_bf16(a0, bp[ks][0], g00, 0,0,0);
      g01 = __builtin_amdgcn_mfma_f32_16x16x32_bf16(a0, bp[ks][1], g01, 0,0,0);
      g10 = __builtin_amdgcn_mfma_f32_16x16x32_bf16(a1, bp[ks][0], g10, 0,0,0);
      g11 = __builtin_amdgcn_mfma_f32_16x16x32_bf16(a1, bp[ks][1], g11, 0,0,0);
      if (wid == 0) {
        short8 wb = *(const short8*)(wsd + (size_t)lr*128 + ks*32 + lq*8);
        s0v = __builtin_amdgcn_mfma_f32_16x16x32_bf16(a0, wb, s0v, 0,0,0);
        s1v = __builtin_amdgcn_mfma_f32_16x16x32_bf16(a1, wb, s1v, 0,0,0);
      }
    }
    f32x4 gg[2][2] = {{g00,g01},{g10,g11}};
    #pragma unroll
    for (int mt=0;mt<2;++mt)
      #pragma unroll
      for (int ct=0;ct<2;++ct){
        int col = wid*32 + ct*16 + lr;
        int row0 = mt*16 + lq*4;
        u32 wv0 = pk2bf(gg[mt][ct][0], gg[mt][ct][1]);
        u32 wv1 = pk2bf(gg[mt][ct][2], gg[mt][ct][3]);
        *(uint2*)&hmT[col*40 + row0] = make_uint2(wv0,wv1);
      }
    if (wid == 0) {
      if (lr < 8) {
        int which = lr >> 2, h = lr & 3;
        #pragma unroll
        for (int r=0;r<4;++r){
          int n0_ = lq*4 + r, n1_ = 16 + lq*4 + r;
          if (n0_ < NNODE) sd[which][n0_][h] = s0v[r];
          if (n1_ < NNODE) sd[which][n1_][h] = s1v[r];
        }
      }
      // maxd[h] over dst cols (padding rows give 0, only raises the shift m' >= max: softmax-invariant)
      float mx = fmaxf(fmaxf(fmaxf(s0v[0],s0v[1]),fmaxf(s0v[2],s0v[3])),
                       fmaxf(fmaxf(s1v[0],s1v[1]),fmaxf(s1v[2],s1v[3])));
      mx = fmaxf(mx, __shfl_xor(mx, 16));
      mx = fmaxf(mx, __shfl_xor(mx, 32));
      if (lq == 0 && lr >= 4 && lr < 8) smax[lr-4] = mx;
    }
  }
  __syncthreads();
  // exp + rowsum; m' = leaky(src_i + maxd_h) >= max_j leaky(src_i + dst_j) (monotone)
  for (int idx = tid; idx < 84*32; idx += 256) {
    int j = idx & 31, ih = idx >> 5;
    int i = ih >> 2, h = ih & 3;
    float sv = sd[0][i][h];
    float mraw = sv + smax[h];
    float m = mraw >= 0.f ? mraw : 0.2f*mraw;
    float ex = 0.f;
    if (j < NNODE){
      float e = sv + sd[1][j][h];
      e = e>=0.f ? e : 0.2f*e;
      ex = __expf(e - m);
    }
    alb[(h*32+i)*40 + j] = (short)f2bf(ex);
    float s = ex;
    #pragma unroll
    for (int off=1; off<32; off<<=1) s += __shfl_xor(s, off);
    if (j == 0) sm[h][i] = 1.f/s;
  }
  __syncthreads();
  {
    int h = wid;
    short8 a0 = *(const short8*)&alb[(h*32 + lr     )*40 + lq*8];
    short8 a1 = *(const short8*)&alb[(h*32 + 16 + lr)*40 + lq*8];
    short8 b0 = *(const short8*)&hmT[(h*32 + lr     )*40 + lq*8];
    short8 b1 = *(const short8*)&hmT[(h*32 + 16 + lr)*40 + lq*8];
    f32x4 c00={},c01={},c10={},c11={};
    c00 = __builtin_amdgcn_mfma_f32_16x16x32_bf16(a0,b0,c00,0,0,0);
    c01 = __builtin_amdgcn_mfma_f32_16x16x32_bf16(a0,b1,c01,0,0,0);
    c10 = __builtin_amdgcn_mfma_f32_16x16x32_bf16(a1,b0,c10,0,0,0);
    c11 = __builtin_amdgcn_mfma_f32_16x16x32_bf16(a1,b1,c11,0,0,0);
    f32x4 cc[2][2] = {{c00,c01},{c10,c11}};
    #pragma unroll
    for (int ct=0; ct<2; ++ct){
      int col = h*32 + ct*16 + lr;
      float s = 0.f;
      #pragma unroll
      for (int mt=0; mt<2; ++mt)
        #pragma unroll
        for (int r=0;r<4;++r){
          int n = mt*16 + lq*4 + r;
          if (n < NNODE)
            s += fmaxf(bf2f((u16)sh0[n*136+col]) + cc[mt][ct][r]*sm[h][n], 0.f);
        }
      s += __shfl_xor(s, 16);
      s += __shfl_xor(s, 32);
      if (lq == 0) fsum_out[(size_t)bt*128 + col] = f2bf(s*(1.f/21.f));
    }
  }
}

// ---------- bf16 MFMA GEMM, 128x128 tile, BK=64, XOR-swizzled LDS ----------
template<int ACC, int BIAS, int RELU, int SM>
__global__ __launch_bounds__(256) void gemm_bf16_kernel(
    const u16* __restrict__ A, const u16* __restrict__ BT, const float* __restrict__ bias,
    float* __restrict__ C, u16* __restrict__ C2,
    int M, int N, int K, int lda)
{
  __shared__ __align__(16) short Asl[8192];
  __shared__ __align__(16) short Bsl[8192];
  int tid = threadIdx.x;
  int lane = tid & 63, wid = tid >> 6;
  int wm = wid >> 1, wn = wid & 1;
  int row0 = blockIdx.y*128, col0 = blockIdx.x*128;
  const u16* Ab = A  + (size_t)row0*lda;
  const u16* Bb = BT + (size_t)col0*K;
  f32x4 acc[4][4] = {};
  int lrow = lane & 15, lk = (lane>>4)*8;
  for (int k0 = 0; k0 < K; k0 += 64) {
    #pragma unroll
    for (int is=0; is<4; ++is){
      int li = is*256 + tid;
      int row = li >> 3;
      int c8  = (li & 7) ^ (row & 7);
      gload16(Ab + (size_t)row*lda + k0 + c8*8, (u16*)Asl + ((is<<8)+(wid<<6))*8);
      gload16(Bb + (size_t)row*K   + k0 + c8*8, (u16*)Bsl + ((is<<8)+(wid<<6))*8);
    }
    __syncthreads();
    #pragma unroll
    for (int ksub=0; ksub<2; ++ksub){
      int slot = (ksub*32 + lk) >> 3;
      short8 a[4], b[4];
      #pragma unroll
      for (int i=0;i<4;++i){ int rr=wm*64+i*16+lrow; a[i]=*(const short8*)&Asl[rr*64+((slot^(rr&7))<<3)]; }
      #pragma unroll
      for (int j=0;j<4;++j){ int rr=wn*64+j*16+lrow; b[j]=*(const short8*)&Bsl[rr*64+((slot^(rr&7))<<3)]; }
      #pragma unroll
      for (int i=0;i<4;++i)
        #pragma unroll
        for (int j=0;j<4;++j)
          acc[i][j] = __builtin_amdgcn_mfma_f32_16x16x32_bf16(a[i], b[j], acc[i][j], 0, 0, 0);
    }
    __syncthreads();
  }
  #pragma unroll
  for (int i=0;i<4;++i) {
    int row = row0 + wm*64 + i*16 + (lane>>4)*4;
    #pragma unroll
    for (int j=0;j<4;++j) {
      int col = col0 + wn*64 + j*16 + (lane&15);
      if (col < N) {
        float bv = BIAS ? bias[col] : 0.f;
        #pragma unroll
        for (int r=0;r<4;++r) {
          float v = acc[i][j][r] + bv;
          if (RELU) v = fmaxf(v, 0.f);
          size_t o = (size_t)(row+r)*N + col;
          if (ACC)           C[o] += v;
          else if (SM == 0)  C[o]  = v;
          else               C2[o] = f2bf(v);
        }
      }
    }
  }
}

// ---------- bf16 MFMA GEMM, BM=64 x BN=128, BK=64 (occupancy tile) ----------
// POOL: per-block column partials of FINAL value (ACC-updated) * 1/256 -> pool
template<int ACC, int BIAS, int RELU, int SM, int POOL>
__global__ __launch_bounds__(256) void gemm_bm64_kernel(
    const u16* __restrict__ A, const u16* __restrict__ BT, const float* __restrict__ bias,
    float* __restrict__ C, u16* __restrict__ C2, float* __restrict__ pool,
    int M, int N, int K, int lda)
{
  __shared__ __align__(16) short Asl[4096];    // [64][64]
  __shared__ __align__(16) short Bsl[8192];    // [128][64]
  int tid = threadIdx.x;
  int lane = tid & 63, wid = tid >> 6;
  int wm = wid >> 1, wn = wid & 1;
  int row0 = blockIdx.y*64, col0 = blockIdx.x*128;
  const u16* Ab = A  + (size_t)row0*lda;
  const u16* Bb = BT + (size_t)col0*K;
  f32x4 acc[2][4] = {};
  int lrow = lane & 15, lq = lane >> 4, lk = lq*8;
  for (int k0 = 0; k0 < K; k0 += 64) {
    #pragma unroll
    for (int is=0; is<2; ++is){
      int li = is*256 + tid;
      int row = li >> 3;
      int c8  = (li & 7) ^ (row & 7);
      gload16(Ab + (size_t)row*lda + k0 + c8*8, (u16*)Asl + ((is<<8)+(wid<<6))*8);
    }
    #pragma unroll
    for (int is=0; is<4; ++is){
      int li = is*256 + tid;
      int row = li >> 3;
      int c8  = (li & 7) ^ (row & 7);
      gload16(Bb + (size_t)row*K + k0 + c8*8, (u16*)Bsl + ((is<<8)+(wid<<6))*8);
    }
    __syncthreads();
    #pragma unroll
    for (int ksub=0; ksub<2; ++ksub){
      int slot = (ksub*32 + lk) >> 3;
      short8 a[2], b[4];
      #pragma unroll
      for (int i=0;i<2;++i){ int rr=wm*32+i*16+lrow; a[i]=*(const short8*)&Asl[rr*64+((slot^(rr&7))<<3)]; }
      #pragma unroll
      for (int j=0;j<4;++j){ int rr=wn*64+j*16+lrow; b[j]=*(const short8*)&Bsl[rr*64+((slot^(rr&7))<<3)]; }
      #pragma unroll
      for (int i=0;i<2;++i)
        #pragma unroll
        for (int j=0;j<4;++j)
          acc[i][j] = __builtin_amdgcn_mfma_f32_16x16x32_bf16(a[i], b[j], acc[i][j], 0, 0, 0);
    }
    __syncthreads();
  }
  float colsum[4] = {0.f,0.f,0.f,0.f};
  #pragma unroll
  for (int i=0;i<2;++i) {
    int row = row0 + wm*32 + i*16 + lq*4;
    #pragma unroll
    for (int j=0;j<4;++j) {
      int col = col0 + wn*64 + j*16 + lrow;
      if (col < N) {
        float bv = BIAS ? bias[col] : 0.f;
        #pragma unroll
        for (int r=0;r<4;++r) {
          float v = acc[i][j][r] + bv;
          if (RELU) v = fmaxf(v, 0.f);
          size_t o = (size_t)(row+r)*N + col;
          float fv;
          if (ACC) { fv = C[o] + v; C[o] = fv; }
          else     { fv = v;
                     if (SM == 0)  C[o]  = v;
                     else          C2[o] = f2bf(v); }
          if (POOL) colsum[j] += fv;
        }
      }
    }
  }
  if (POOL) {
    float* red = (float*)Asl;
    #pragma unroll
    for (int j=0;j<4;++j) red[tid*4+j] = colsum[j];
    __syncthreads();
    if (tid < 128) {
      int wn_ = tid >> 6, j_ = (tid >> 4) & 3, l15 = tid & 15;
      float s = 0.f;
      #pragma unroll
      for (int wm_=0;wm_<2;++wm_)
        #pragma unroll
        for (int g=0;g<4;++g)
          s += red[(((wm_*2+wn_)*64) + g*16 + l15)*4 + j_];
      pool[(size_t)blockIdx.y*256 + blockIdx.x*128 + tid] = s * (1.f/256.f);
    }
  }
}

// ---------- x_proj GEMM: C[M][128], col-block d = dir; K=512, no padding ----------
__global__ __launch_bounds__(256) void gemm_xproj_kernel(
    const u16* __restrict__ A, const u16* __restrict__ BT, float* __restrict__ C)
{
  __shared__ __align__(16) short Asl[4096];    // [64][64]
  __shared__ __align__(16) short Bsl[4096];    // [64][64]
  int tid = threadIdx.x;
  int lane = tid & 63, wid = tid >> 6;
  int lrow = lane & 15, lq = lane >> 4, lk = lq*8;
  int d = blockIdx.x, row0 = blockIdx.y*64;
  const u16* Ab = A  + (size_t)row0*1024 + d*512;
  const u16* Bb = BT + (size_t)d*32768;
  f32x4 acc[4] = {};
  for (int k0 = 0; k0 < 512; k0 += 64) {
    #pragma unroll
    for (int is=0; is<2; ++is){
      int li = is*256 + tid;
      int row = li >> 3;
      int c8  = (li & 7) ^ (row & 7);
      gload16(Ab + (size_t)row*1024 + k0 + c8*8, (u16*)Asl + ((is<<8)+(wid<<6))*8);
      gload16(Bb + (size_t)row*512  + k0 + c8*8, (u16*)Bsl + ((is<<8)+(wid<<6))*8);
    }
    __syncthreads();
    #pragma unroll
    for (int ksub=0; ksub<2; ++ksub){
      int slot = (ksub*32 + lk) >> 3;
      int arr = wid*16 + lrow;
      short8 av = *(const short8*)&Asl[arr*64 + ((slot^(arr&7))<<3)];
      #pragma unroll
      for (int j=0;j<4;++j){
        int brr = j*16 + lrow;
        short8 bv = *(const short8*)&Bsl[brr*64 + ((slot^(brr&7))<<3)];
        acc[j] = __builtin_amdgcn_mfma_f32_16x16x32_bf16(av, bv, acc[j], 0, 0, 0);
      }
    }
    __syncthreads();
  }
  #pragma unroll
  for (int j=0;j<4;++j){
    int col = d*64 + j*16 + lrow;
    #pragma unroll
    for (int r=0;r<4;++r){
      int row = row0 + wid*16 + lq*4 + r;
      C[(size_t)row*128 + col] = acc[j][r];
    }
  }
}

// ---------- LayerNorm -> bf16 ----------
__global__ __launch_bounds__(256) void ln_kernel(const float* __restrict__ x,
    const float* __restrict__ w, u16* __restrict__ o)
{
  int row = blockIdx.x*4 + (threadIdx.x>>6);
  int lane = threadIdx.x & 63;
  float4 v = *(const float4*)(x + (size_t)row*DMODEL + lane*4);
  float s = v.x+v.y+v.z+v.w;
  #pragma unroll
  for (int off=32;off>=1;off>>=1) s += __shfl_xor(s, off);
  float mu = s * (1.f/256.f);
  float d0=v.x-mu, d1=v.y-mu, d2=v.z-mu, d3=v.w-mu;
  float q = d0*d0+d1*d1+d2*d2+d3*d3;
  #pragma unroll
  for (int off=32;off>=1;off>>=1) q += __shfl_xor(q, off);
  float inv = 1.f/sqrtf(q*(1.f/256.f) + 1e-5f);
  float4 wv = *(const float4*)(w + lane*4);
  uint2 pk; pk.x = pk2bf(d0*inv*wv.x, d1*inv*wv.y); pk.y = pk2bf(d2*inv*wv.z, d3*inv*wv.w);
  *(uint2*)(o + (size_t)row*DMODEL + lane*4) = pk;
}

// ---------- depthwise conv + silu, 8 channels x 4 timesteps per thread ----------
__global__ __launch_bounds__(256) void conv_kernel(const u16* __restrict__ xz,
    const float* __restrict__ cw, const float* __restrict__ cb,
    u16* __restrict__ ucv)
{
  int idx = blockIdx.x*256 + threadIdx.x;          // BTT/4 * 128 = 524288
  int du8 = idx & 127, dir = du8 >> 6, d8 = (du8 & 63) << 3;
  int btq = idx >> 7;                              // 0..4095
  int bt0 = btq << 2, t0 = bt0 & 255;
  const u16* up = xz + (size_t)(bt0 - t0)*2048 + dir*512 + d8;   // base of this b
  float w[8][4];
  #pragma unroll
  for (int j=0;j<8;++j){
    float4 wv = *(const float4*)(cw + (size_t)dir*2048 + (d8+j)*4);
    w[j][0]=wv.x; w[j][1]=wv.y; w[j][2]=wv.z; w[j][3]=wv.w;
  }
  float bias[8];
  {
    float4 cb0 = *(const float4*)(cb + dir*512 + d8);
    float4 cb1 = *(const float4*)(cb + dir*512 + d8 + 4);
    bias[0]=cb0.x; bias[1]=cb0.y; bias[2]=cb0.z; bias[3]=cb0.w;
    bias[4]=cb1.x; bias[5]=cb1.y; bias[6]=cb1.z; bias[7]=cb1.w;
  }
  // taps: dir0 -> t0-3..t0+3 ; dir1 -> t0..t0+6
  short8 tap[7];
  #pragma unroll
  for (int j=0;j<7;++j){
    int tt = dir ? (t0 + j) : (t0 - 3 + j);
    if (tt >= 0 && tt < TT) {
      tap[j] = *(const short8*)(up + (size_t)tt*2048);
    } else {
      short8 z;
      for (int e=0;e<8;++e) z[e]=0;
      tap[j]=z;
    }
  }
  #pragma unroll
  for (int q=0;q<4;++q){
    float s[8];
    #pragma unroll
    for (int j=0;j<8;++j) s[j] = bias[j];
    if (dir == 0){
      #pragma unroll
      for (int k=0;k<4;++k){
        const short8& tv = tap[q+k];
        #pragma unroll
        for (int j=0;j<8;++j) s[j] += w[j][k]*bf2f((u16)tv[j]);
      }
    } else {
      #pragma unroll
      for (int kk=0;kk<4;++kk){
        const short8& tv = tap[q+kk];
        #pragma unroll
        for (int j=0;j<8;++j) s[j] += w[j][3-kk]*bf2f((u16)tv[j]);
      }
    }
    short8 o;
    #pragma unroll
    for (int j=0;j<8;++j) o[j] = (short)f2bf(siluf(s[j]));
    *(short8*)(ucv + (size_t)(bt0+q)*1024 + dir*512 + d8) = o;
  }
}

// ---------- chunked selective scan, pow-chain dA (guarded) ----------
// grid (64 b, {7|8} c, 4 = d*2 + half)
template<int FINAL>
__global__ __launch_bounds__(256) void scan_phase_kernel(
    const u16* __restrict__ ucv, const float* __restrict__ xd, const u16* __restrict__ xz,
    const float* __restrict__ dtw, const float* __restrict__ dtb,
    const float* __restrict__ alog, const float* __restrict__ dvec,
    const u16* __restrict__ hend_r, const float* __restrict__ sdt_r,
    float* __restrict__ sdt_w, u16* __restrict__ hend_w,
    u16* __restrict__ yout)
{
  int b = blockIdx.x, c = blockIdx.y, gz = blockIdx.z;
  int d = gz >> 1;
  int tid = threadIdx.x;
  int dd = ((gz & 1) << 8) + tid;
  float wdt[16], Av[16], h[16];
  #pragma unroll
  for (int s=0;s<16;++s){
    wdt[s] = dtw[d*8192 + s*512 + dd];
    Av[s]  = -__expf(alog[d*8192 + dd*16 + s]);
    h[s]   = 0.f;
  }
  float bdt = dtb[d*512 + dd];
  bool powok = true;
  #pragma unroll
  for (int s=0;s<16;++s) powok = powok && (fabsf(Av[s] + (float)(s+1)) < 1e-5f*(float)(s+1));
  __shared__ float sxd[32][48];
  if (FINAL) {
    for (int i = tid; i < 1536; i += 256){
      int q = i/48, r = i - q*48;
      int p = (c<<5)+q, t = d ? 255-p : p;
      sxd[q][r] = xd[((size_t)b*TT + t)*128 + d*64 + r];
    }
  } else {
    for (int i = tid; i < 1024; i += 256){
      int q = i>>5, r = i&31;
      int p = (c<<5)+q, t = d ? 255-p : p;
      sxd[q][r] = xd[((size_t)b*TT + t)*128 + d*64 + r];
    }
  }
  if (FINAL) {
    if (powok) {
      for (int cp=0; cp<c; ++cp){
        size_t cbase = (((size_t)b*8+cp)*2+d)*512 + dd;
        float S = sdt_r[cbase];
        float e1 = __expf(-S);
        short8 h0v = *(const short8*)(hend_r + cbase*16);
        short8 h1v = *(const short8*)(hend_r + cbase*16 + 8);
        float pw = e1;
        #pragma unroll
        for (int s=0;s<8;++s){ h[s] = fmaf(pw, h[s], bf2f((u16)h0v[s])); pw *= e1; }
        #pragma unroll
        for (int s=0;s<8;++s){ h[s+8] = fmaf(pw, h[s+8], bf2f((u16)h1v[s])); pw *= e1; }
      }
    } else {
      for (int cp=0; cp<c; ++cp){
        size_t cbase = (((size_t)b*8+cp)*2+d)*512 + dd;
        float S = sdt_r[cbase];
        short8 h0v = *(const short8*)(hend_r + cbase*16);
        short8 h1v = *(const short8*)(hend_r + cbase*16 + 8);
        #pragma unroll
        for (int s=0;s<8;++s)  h[s]   = fmaf(__expf(Av[s]*S),   h[s],   bf2f((u16)h0v[s]));
        #pragma unroll
        for (int s=0;s<8;++s)  h[s+8] = fmaf(__expf(Av[s+8]*S), h[s+8], bf2f((u16)h1v[s]));
      }
    }
  }
  __syncthreads();
  float S = 0.f;
  float Dv = FINAL ? dvec[d*512 + dd] : 0.f;
  const u16* ub = ucv + d*512 + dd;
  const u16* zb = xz + 1024 + d*512 + dd;
  u16* yb = yout + d*512 + dd;
  auto qloop = [&](auto icpow){
    constexpr int POW = decltype(icpow)::v;
    #pragma unroll 4
    for (int q=0;q<32;++q) {
      int p = (c<<5)+q, t = d ? 255-p : p;
      size_t row = (size_t)b*TT + t;
      float uc = bf2f(ub[row*1024]);
      float zc = FINAL ? bf2f(zb[row*2048]) : 0.f;
      const float* sr = sxd[q];
      float p0=0.f,p1=0.f,p2=0.f,p3=0.f;
      #pragma unroll
      for (int r=0;r<16;r+=4){
        p0 = fmaf(sr[r+0],wdt[r+0],p0);
        p1 = fmaf(sr[r+1],wdt[r+1],p1);
        p2 = fmaf(sr[r+2],wdt[r+2],p2);
        p3 = fmaf(sr[r+3],wdt[r+3],p3);
      }
      float dtp = bdt + ((p0+p1)+(p2+p3));
      float dt = fmaxf(dtp,0.f) + __logf(1.f + __expf(-fabsf(dtp)));
      float dtu = dt*uc;
      if (!FINAL) S += dt;
      float y0=0.f, y1=0.f;
      if (POW) {
        float rr = __expf(-dt);
        float pw = rr;
        #pragma unroll
        for (int s=0;s<16;++s){
          h[s] = fmaf(pw, h[s], dtu*sr[16+s]);
          if (FINAL) y0 = fmaf(h[s], sr[32+s], y0);
          pw *= rr;
        }
      } else {
        #pragma unroll
        for (int s=0;s<16;s+=2){
          float dA0 = __expf(dt*Av[s]);
          float dA1 = __expf(dt*Av[s+1]);
          h[s]   = fmaf(dA0, h[s],   dtu*sr[16+s]);
          h[s+1] = fmaf(dA1, h[s+1], dtu*sr[16+s+1]);
          if (FINAL){ y0 = fmaf(h[s],sr[32+s],y0); y1 = fmaf(h[s+1],sr[32+s+1],y1); }
        }
      }
      if (FINAL){
        float yv = (y0+y1) + uc*Dv;
        float sg = zc / (1.f + __expf(-zc));
        yb[row*2048] = f2bf(yv*sg);
      }
    }
  };
  if (powok) qloop(IC<1>{}); else qloop(IC<0>{});
  if (!FINAL){
    size_t co = (((size_t)b*8+c)*2+d)*512 + dd;
    sdt_w[co] = S;
    short8 o0, o1;
    #pragma unroll
    for (int s=0;s<8;++s){ o0[s] = (short)f2bf(h[s]); o1[s] = (short)f2bf(h[s+8]); }
    *(short8*)(hend_w + co*16)     = o0;
    *(short8*)(hend_w + co*16 + 8) = o1;
  }
}

// ---------- emb: temporal mean (from out_proj pool partials) + sign GEMV ----------
__global__ __launch_bounds__(256) void emb_kernel(const float* __restrict__ part_m,
    const float* __restrict__ wsgn, const float* __restrict__ bsgn,
    float* __restrict__ embw, float* __restrict__ out)
{
  int b = blockIdx.x, tid = threadIdx.x;
  __shared__ float mt[256];
  mt[tid] = part_m[(size_t)(4*b)*256 + tid] + part_m[(size_t)(4*b+1)*256 + tid]
          + part_m[(size_t)(4*b+2)*256 + tid] + part_m[(size_t)(4*b+3)*256 + tid];
  __syncthreads();
  float acc = bsgn[tid];
  for (int i=0;i<DMODEL;++i) acc += mt[i]*wsgn[i*DMODEL + tid];
  embw[b*DMODEL+tid] = acc;
  out[128000 + b*DMODEL + tid] = acc;
}

// ---------- head+sims fused: grid (64, 5); qt<4 sign logits, qt==4 sims ----------
__global__ __launch_bounds__(256) void head_kernel(const float* __restrict__ embw,
    const float* __restrict__ protos, const float* __restrict__ part,
    const float* __restrict__ phs, const float* __restrict__ ploc,
    const float* __restrict__ pmov, const float* __restrict__ pori,
    float* __restrict__ out)
{
  int b = blockIdx.x, qt = blockIdx.y, tid = threadIdx.x;
  __shared__ __align__(16) float e[256];
  __shared__ float red[4];
  if (qt == 4) {
    e[tid] = part[(size_t)(4*b)*256 + tid] + part[(size_t)(4*b+1)*256 + tid]
           + part[(size_t)(4*b+2)*256 + tid] + part[(size_t)(4*b+3)*256 + tid];
    __syncthreads();
    if (tid < 4) {
      float ss = 0.f;
      for (int i=0;i<64;++i){ float q = e[tid*64+i]; ss += q*q; }
      red[tid] = 1.f/(sqrtf(ss)+1e-8f);
    }
    __syncthreads();
    if (tid < 88) {
      int k, pi; const float* P; size_t off; int npk;
      if (tid < 40)      { k=0; pi=tid;    P=phs;  off=144384; npk=40; }
      else if (tid < 60) { k=1; pi=tid-40; P=ploc; off=146944; npk=20; }
      else if (tid < 80) { k=2; pi=tid-60; P=pmov; off=148224; npk=20; }
      else               { k=3; pi=tid-80; P=pori; off=149504; npk=8;  }
      float dot=0.f, ps=0.f;
      for (int i=0;i<64;++i){ float pv = P[pi*64+i]; dot += pv*e[k*64+i]; ps += pv*pv; }
      out[off + (size_t)b*npk + pi] = dot*red[k]/(sqrtf(ps)+1e-8f)*(1.f/0.07f);
    }
    return;
  }
  float acc = embw[b*DMODEL + tid];
  e[tid] = acc;
  __syncthreads();
  float v = acc*acc;
  #pragma unroll
  for (int off=32;off>=1;off>>=1) v += __shfl_xor(v, off);
  if ((tid&63)==0) red[tid>>6] = v;
  __syncthreads();
  float esc = 1.f/(sqrtf(red[0]+red[1]+red[2]+red[3]) + 1e-8f);
  int pend = qt*500 + 500;
  for (int p = qt*500 + tid; p < pend; p += 256) {
    const float* pr = protos + (size_t)p*256;
    float dot=0.f, ps=0.f;
    for (int i=0;i<256;i+=4) {
      float4 pv = *(const float4*)(pr+i);
      float4 ev = *(const float4*)(e+i);
      dot += pv.x*ev.x + pv.y*ev.y + pv.z*ev.z + pv.w*ev.w;
      ps  += pv.x*pv.x + pv.y*pv.y + pv.z*pv.z + pv.w*pv.w;
    }
    out[(size_t)b*NSIGNS + p] = dot*esc/(sqrtf(ps)+1e-8f)*(1.f/0.07f);
  }
}

extern "C" void kernel_launch(void* const* d_in, const int* in_sizes, int n_in,
                              void* d_out, int out_size, void* d_ws, size_t ws_size,
                              hipStream_t stream) {
  const float* x         = (const float*)d_in[0];
  const float* w_in      = (const float*)d_in[1];
  const float* b_in      = (const float*)d_in[2];
  const float* w_gat     = (const float*)d_in[3];
  const float* a_src     = (const float*)d_in[4];
  const float* a_dst     = (const float*)d_in[5];
  const float* w_out     = (const float*)d_in[6];
  const float* b_out     = (const float*)d_in[7];
  const float* pdm_w     = (const float*)d_in[8];
  const float* pdm_b     = (const float*)d_in[9];
  const float* w_fuse    = (const float*)d_in[10];
  const float* b_fuse    = (const float*)d_in[11];
  const float* ln_w      = (const float*)d_in[12];
  const float* in_proj   = (const float*)d_in[13];
  const float* conv_w    = (const float*)d_in[14];
  const float* conv_b    = (const float*)d_in[15];
  const float* x_proj    = (const float*)d_in[16];
  const float* dt_w      = (const float*)d_in[17];
  const float* dt_b      = (const float*)d_in[18];
  const float* A_log     = (const float*)d_in[19];
  const float* Dvec      = (const float*)d_in[20];
  const float* out_proj  = (const float*)d_in[21];
  const float* w_sign    = (const float*)d_in[22];
  const float* b_sign    = (const float*)d_in[23];
  const float* protos    = (const float*)d_in[24];
  const float* phs       = (const float*)d_in[25];
  const float* ploc      = (const float*)d_in[26];
  const float* pmov      = (const float*)d_in[27];
  const float* pori      = (const float*)d_in[28];
  float* out = (float*)d_out;

  // ---- ws layout ----
  float* wsf = (float*)d_ws;
  const size_t f_xx    = 0;                          // 16384*256
  const size_t f_xdbl  = f_xx    + 4194304;          // 16384*128
  const size_t f_part  = f_xdbl  + 2097152;          // 256*256  (comps pool)
  const size_t f_mpart = f_part  + 65536;            // 256*256  (final xx mean pool)
  const size_t f_emb   = f_mpart + 65536;            // 64*256
  const size_t f_end   = f_emb   + 16384;
  u16* wsu = (u16*)(wsf + f_end);
  const size_t u_xn    = 0;                          // 16384*256
  const size_t u_xz    = u_xn   + 4194304;           // 16384*2048 [u0 u1 z0 z1]; y -> u slots
  const size_t u_ucv   = u_xz   + 33554432;          // 16384*1024
  const size_t u_fsum  = u_ucv  + 16777216;          // 16384*128
  const size_t u_spat  = u_fsum + 2097152;           // 16384*256
  const size_t u_comps = u_spat + 4194304;           // 16384*256
  const size_t u_w     = u_comps+ 4194304;           // weights
  u16* wiT = wsu + u_w;
  u16* woT = wiT + 2097152;
  u16* wxT = woT + 1048576;
  u16* wA  = wxT + 524288;
  u16* wB  = wA  + 32768;
  u16* wF  = wB  + 65536;
  u16* wBp = wF  + 65536;
  u16* wSd = wBp + 16384;              // [16][128] folded sd weights
  // scan scratch aliases fsum/spat/comps (dead during SSM loop)
  u16*   hstate = wsu + u_fsum;                      // 64*8*2*512*16 u16 = 16MB
  float* sdt    = (float*)(wsu + u_fsum + 8388608);  // 64*8*2*512 f32 = 2MB

  transpose_w_kernel<<<945, 256, 0, stream>>>(in_proj, out_proj, x_proj, w_out, pdm_w, w_fuse, w_gat, a_src, a_dst, wsu + u_w);
  agan_kernel<<<BTT, 256, 0, stream>>>(x, w_in, b_in, wBp, wSd, wsu + u_fsum);
  gemm_bm64_kernel<0,1,0,1,0><<<dim3(2,256), 256, 0, stream>>>(wsu+u_fsum, wA, b_out, nullptr, wsu+u_spat, nullptr, BTT, 256, 128, 128);
  gemm_bm64_kernel<0,1,1,1,1><<<dim3(2,256), 256, 0, stream>>>(wsu+u_spat, wB, pdm_b, nullptr, wsu+u_comps, wsf+f_part, BTT, 256, 256, 256);
  gemm_bm64_kernel<0,1,0,0,0><<<dim3(2,256), 256, 0, stream>>>(wsu+u_comps, wF, b_fuse, wsf+f_xx, nullptr, nullptr, BTT, 256, 256, 256);

  for (int l = 0; l < 4; ++l) {
    ln_kernel<<<BTT/4, 256, 0, stream>>>(wsf+f_xx, ln_w + l*DMODEL, wsu+u_xn);
    gemm_bf16_kernel<0,0,0,1><<<dim3(16,128), 256, 0, stream>>>(wsu+u_xn, wiT + (size_t)l*524288,
        nullptr, nullptr, wsu+u_xz, BTT, 2048, 256, 256);
    conv_kernel<<<BTT*128/(4*256), 256, 0, stream>>>(wsu+u_xz, conv_w + (size_t)l*4096,
        conv_b + (size_t)l*1024, wsu+u_ucv);
    gemm_xproj_kernel<<<dim3(2,256), 256, 0, stream>>>(wsu+u_ucv, wxT + (size_t)l*131072, wsf+f_xdbl);
    scan_phase_kernel<0><<<dim3(64,7,4), 256, 0, stream>>>(wsu+u_ucv, wsf+f_xdbl, nullptr,
        dt_w + (size_t)l*16384, dt_b + (size_t)l*1024,
        A_log + (size_t)l*16384, nullptr,
        nullptr, nullptr, sdt, hstate, nullptr);
    scan_phase_kernel<1><<<dim3(64,8,4), 256, 0, stream>>>(wsu+u_ucv, wsf+f_xdbl, wsu+u_xz,
        dt_w + (size_t)l*16384, dt_b + (size_t)l*1024,
        A_log + (size_t)l*16384, Dvec + (size_t)l*1024,
        hstate, sdt, nullptr, nullptr, wsu+u_xz);
    if (l < 3)
      gemm_bm64_kernel<1,0,0,0,0><<<dim3(2,256), 256, 0, stream>>>(wsu+u_xz, woT + (size_t)l*262144,
          nullptr, wsf+f_xx, nullptr, nullptr, BTT, 256, 1024, 2048);
    else
      gemm_bm64_kernel<1,0,0,0,1><<<dim3(2,256), 256, 0, stream>>>(wsu+u_xz, woT + (size_t)l*262144,
          nullptr, wsf+f_xx, nullptr, wsf+f_mpart, BTT, 256, 1024, 2048);
  }

  emb_kernel<<<64, 256, 0, stream>>>(wsf+f_mpart, w_sign, b_sign, wsf+f_emb, out);
  head_kernel<<<dim3(64,5), 256, 0, stream>>>(wsf+f_emb, protos, wsf+f_part, phs, ploc, pmov, pori, out);
  (void)in_sizes; (void)n_in; (void)out_size; (void)ws_size;
}